// Round 8
// baseline (665.626 us; speedup 1.0000x reference)
//
#include <hip/hip_runtime.h>
#include <math.h>

// Problem dims
#define NB 128
#define NN 36
#define S37 37            // padded stride (xseq_k)
#define S40 40            // padded stride, 16B-aligned rows (iter_k)
#define NFEAT 2048
#define NMID 517
#define KP 544            // padded K (multiple of 32) for MID-dim GEMMs
#define NHID 128
#define NOUT 1024
#define ROWS (NB*NN)      // 4608

typedef __bf16 bf16x8 __attribute__((ext_vector_type(8)));
typedef float  f32x4  __attribute__((ext_vector_type(4)));

__device__ __forceinline__ float sigf(float x){ return 1.f/(1.f+expf(-x)); }
__device__ __forceinline__ unsigned short f2bf(float x){
    unsigned u = __float_as_uint(x);
    return (unsigned short)((u + 0x7FFFu + ((u>>16)&1u)) >> 16);
}
__device__ __forceinline__ float bf2f(unsigned short b){
    return __uint_as_float(((unsigned)b) << 16);
}

// ---------------------------------------------------------------------------
// prep_all: ALL input casts/reorders/zeroing in one dispatch.
// Now also emits feats_bf cols 0..4 (boxes/att) and zero-pads cols 517..543
// (was conv_reduce's job; conv epilogue only covers cols 5..516).
// ---------------------------------------------------------------------------
__global__ __launch_bounds__(256) void prep_all(
    const float* __restrict__ boxes, const float* __restrict__ att,
    const float* __restrict__ features, const float* __restrict__ conv_w,
    const float* __restrict__ wx, const float* __restrict__ wy,
    const float* __restrict__ b1, const float* __restrict__ w_ih,
    const float* __restrict__ w_hh, const float* __restrict__ b_ih,
    const float* __restrict__ b_hh,
    unsigned short* __restrict__ features_bf, unsigned short* __restrict__ convw_bf,
    unsigned short* __restrict__ wxy_bf, float* __restrict__ hxy_b,
    unsigned short* __restrict__ wih_il, unsigned short* __restrict__ whh_il,
    float* __restrict__ comb_b, unsigned int* __restrict__ bar,
    float* __restrict__ feats, unsigned short* __restrict__ feats_bf)
{
    int gtid = blockIdx.x*256 + threadIdx.x;
    int gs = gridDim.x*256;
    if (gtid < 128*64) {
        int b = gtid >> 6, t = gtid & 63;
        float mx = -1e30f;
        for (int idx = t; idx < 4*NN; idx += 64) mx = fmaxf(mx, boxes[b*4*NN + idx]);
        for (int off = 32; off > 0; off >>= 1) mx = fmaxf(mx, __shfl_down(mx, off));
        mx = __shfl(mx, 0);
        float inv = 1.f / mx;
        for (int idx = t; idx < 4*NN; idx += 64) {
            int r = idx / NN, n = idx - r*NN;
            float v = boxes[b*4*NN + idx] * inv;
            feats[(size_t)(b*NN+n)*NMID + r] = v;
            feats_bf[(size_t)(b*NN+n)*KP + r] = f2bf(v);
        }
        if (t < NN) {
            float av = att[b*NN + t];
            feats[(size_t)(b*NN+t)*NMID + 4] = av;
            feats_bf[(size_t)(b*NN+t)*KP + 4] = f2bf(av);
        }
    }
    for (int i = gtid; i < ROWS*27; i += gs) {
        int r = i / 27, cc = i - r*27;
        feats_bf[(size_t)r*KP + 517 + cc] = 0;
    }
    for (int i = gtid; i < ROWS*NFEAT; i += gs) features_bf[i] = f2bf(features[i]);
    for (int i = gtid; i < 512*NFEAT; i += gs) convw_bf[i] = f2bf(conv_w[i]);
    for (int i = gtid; i < 256*KP; i += gs) {
        int r = i / KP, k = i - r*KP;
        float v = 0.f;
        if (k < NMID) v = (r < NHID) ? wx[(size_t)r*NMID+k] : wy[(size_t)(r-NHID)*NMID+k];
        wxy_bf[i] = f2bf(v);
    }
    for (int i = gtid; i < 256; i += gs) hxy_b[i] = (i < NHID) ? b1[i] : 0.f;
    for (int i = gtid; i < 4*NOUT*KP; i += gs) {
        int row = i / KP, k = i - row*KP;
        int u = row >> 2, g = row & 3;
        wih_il[i] = (k < NMID) ? f2bf(w_ih[(size_t)(g*NOUT+u)*NMID + k]) : (unsigned short)0;
    }
    for (int i = gtid; i < 4*NOUT*NOUT; i += gs) {
        int row = i >> 10, k = i & 1023;
        int u = row >> 2, g = row & 3;
        whh_il[i] = f2bf(w_hh[(size_t)(g*NOUT+u)*NOUT + k]);
    }
    for (int i = gtid; i < 4*NOUT; i += gs) {
        int u = i >> 2, g = i & 3;
        comb_b[i] = b_ih[g*NOUT+u] + b_hh[g*NOUT+u];
    }
    // persistent-LSTM producer flags: 4 bt-groups x 128 blocks, monotonic epoch
    for (int i = gtid; i < 512; i += gs) bar[i] = 0u;
}

// ---------------------------------------------------------------------------
// conv64: fused conv GEMM. C[r, m] = sum_f features[r,f]*conv_w[m,f] + bias,
// written DIRECTLY as feats f32 (cols 5..516) and feats_bf bf16 — no split-K
// partials, no conv_reduce (r7 profile: partial round-trip was 75 MB of HBM
// traffic and the old conv gemm128 ran at 1.75 TB/s / 15% MfmaUtil).
// Tile 64x64, 4 waves = 2x2, wave tile 32x32 (4 MFMA / iter), K=2048 unsplit.
// Grid (512/64, 4608/64) = (8, 72) = 576 blocks.
// ---------------------------------------------------------------------------
__global__ __launch_bounds__(256) void conv64(
    const unsigned short* __restrict__ A, const unsigned short* __restrict__ B,
    const float* __restrict__ bias, float* __restrict__ feats,
    unsigned short* __restrict__ feats_bf)
{
    __shared__ __align__(16) char As[4096];
    __shared__ __align__(16) char Bs[4096];
    int n0 = blockIdx.x * 64, m0 = blockIdx.y * 64;
    int tid = threadIdx.x;
    int lane = tid & 63, wave = tid >> 6;
    int wm = wave >> 1, wn = wave & 1;
    f32x4 acc[2][2];
    #pragma unroll
    for (int i = 0; i < 2; ++i)
        #pragma unroll
        for (int j = 0; j < 2; ++j) acc[i][j] = (f32x4){0.f,0.f,0.f,0.f};

    int r = tid >> 2, q = tid & 3;
    const unsigned short* Arow = A + (size_t)(m0+r)*NFEAT + q*8;
    const unsigned short* Brow = B + (size_t)(n0+r)*NFEAT + q*8;
    int sa = ((r>>4)<<10) + (q<<8) + ((r&15)<<4);

    for (int k0 = 0; k0 < NFEAT; k0 += 32) {
        *(uint4*)(As + sa) = *(const uint4*)(Arow + k0);
        *(uint4*)(Bs + sa) = *(const uint4*)(Brow + k0);
        __syncthreads();
        bf16x8 af[2], bfr[2];
        #pragma unroll
        for (int i = 0; i < 2; ++i) af[i]  = *(bf16x8*)(As + ((wm*2+i)<<10) + (lane<<4));
        #pragma unroll
        for (int j = 0; j < 2; ++j) bfr[j] = *(bf16x8*)(Bs + ((wn*2+j)<<10) + (lane<<4));
        #pragma unroll
        for (int i = 0; i < 2; ++i)
            #pragma unroll
            for (int j = 0; j < 2; ++j)
                acc[i][j] = __builtin_amdgcn_mfma_f32_16x16x32_bf16(af[i], bfr[j], acc[i][j], 0, 0, 0);
        __syncthreads();
    }
    int colf = lane & 15, rowq = lane >> 4;
    #pragma unroll
    for (int j = 0; j < 2; ++j) {
        int col = n0 + (wn*2+j)*16 + colf;
        float bv = bias[col];
        #pragma unroll
        for (int i = 0; i < 2; ++i) {
            #pragma unroll
            for (int reg = 0; reg < 4; ++reg) {
                int row = m0 + (wm*2+i)*16 + rowq*4 + reg;
                float v = acc[i][j][reg] + bv;
                feats[(size_t)row*NMID + 5 + col] = v;
                feats_bf[(size_t)row*KP + 5 + col] = f2bf(v);
            }
        }
    }
}

// ---------------------------------------------------------------------------
// gemm128: C[m,n] = sum_k A[m,k]*B[n,k] (+ bias). Block tile 128x128,
// 4 waves = 2x2, wave tile 64x64 (16 MFMA / 8 ds_read_b128 per iter).
// XOR-swizzled LDS (r' = r ^ (q<<2)) -> conflict-free stores AND reads.
// (split-K path retained but unused since conv moved to conv64)
// ---------------------------------------------------------------------------
__global__ __launch_bounds__(256) void gemm128(
    const unsigned short* __restrict__ A, const unsigned short* __restrict__ B,
    const float* __restrict__ bias, void* __restrict__ Cp,
    int Ksl, int lda, int ldb, int ldc, int obf, long long pstride)
{
    __shared__ __align__(16) char As[16384];
    __shared__ __align__(16) char Bs[16384];
    int m0 = blockIdx.y * 128, n0 = blockIdx.x * 128;
    int kbeg = blockIdx.z * Ksl;
    int tid = threadIdx.x;
    int lane = tid & 63, wave = tid >> 6;
    int wm = wave >> 1, wn = wave & 1;
    int sw = ((lane>>4)<<8) + (((lane&15) ^ ((lane>>4)<<2))<<4);
    f32x4 acc[4][4];
    #pragma unroll
    for (int i = 0; i < 4; ++i)
        #pragma unroll
        for (int j = 0; j < 4; ++j) acc[i][j] = (f32x4){0.f,0.f,0.f,0.f};

    for (int k0 = 0; k0 < Ksl; k0 += 32) {
        #pragma unroll
        for (int p = 0; p < 2; ++p) {
            int cc = p*256 + tid;
            int r = cc >> 2, q = cc & 3;
            int sa = ((r>>4)<<10) + (q<<8) + ((((r&15) ^ (q<<2)))<<4);
            uint4 va = *(const uint4*)(A + (size_t)(m0+r)*lda + kbeg + k0 + q*8);
            *(uint4*)(As + sa) = va;
            uint4 vb = *(const uint4*)(B + (size_t)(n0+r)*ldb + kbeg + k0 + q*8);
            *(uint4*)(Bs + sa) = vb;
        }
        __syncthreads();
        bf16x8 af[4], bfr[4];
        #pragma unroll
        for (int i = 0; i < 4; ++i) af[i]  = *(bf16x8*)(As + ((wm*4+i)<<10) + sw);
        #pragma unroll
        for (int j = 0; j < 4; ++j) bfr[j] = *(bf16x8*)(Bs + ((wn*4+j)<<10) + sw);
        #pragma unroll
        for (int i = 0; i < 4; ++i)
            #pragma unroll
            for (int j = 0; j < 4; ++j)
                acc[i][j] = __builtin_amdgcn_mfma_f32_16x16x32_bf16(af[i], bfr[j], acc[i][j], 0, 0, 0);
        __syncthreads();
    }
    int colf = lane & 15, rowq = lane >> 4;
    #pragma unroll
    for (int j = 0; j < 4; ++j) {
        int col = n0 + (wn*4+j)*16 + colf;
        float bv = bias ? bias[col] : 0.f;
        #pragma unroll
        for (int i = 0; i < 4; ++i) {
            #pragma unroll
            for (int reg = 0; reg < 4; ++reg) {
                int row = m0 + (wm*4+i)*16 + rowq*4 + reg;
                float v = acc[i][j][reg] + bv;
                if (obf) ((unsigned short*)Cp)[(size_t)row*ldc + col] = f2bf(v);
                else ((float*)Cp + (size_t)blockIdx.z*pstride)[(size_t)row*ldc + col] = v;
            }
        }
    }
}

// ---------------------------------------------------------------------------
// bf16 MFMA GEMM (hxy only): tile 128x64, wave tile 64x32.
// ---------------------------------------------------------------------------
__global__ __launch_bounds__(256) void gemm_mfma(
    const unsigned short* __restrict__ A, const unsigned short* __restrict__ B,
    const float* __restrict__ bias, void* __restrict__ Cp,
    int K, int lda, int ldb, int ldc, int obf)
{
    __shared__ __align__(16) char As[8192];
    __shared__ __align__(16) char Bs[4096];
    int m0 = blockIdx.y * 128, n0 = blockIdx.x * 64;
    int tid = threadIdx.x;
    int lane = tid & 63, wave = tid >> 6;
    int wm = wave >> 1, wn = wave & 1;
    f32x4 acc[4][2];
    #pragma unroll
    for (int i = 0; i < 4; ++i)
        #pragma unroll
        for (int j = 0; j < 2; ++j) acc[i][j] = (f32x4){0.f,0.f,0.f,0.f};

    for (int k0 = 0; k0 < K; k0 += 32) {
        #pragma unroll
        for (int cc = tid; cc < 512; cc += 256) {
            int r = cc >> 2, q = cc & 3;
            uint4 v = *(const uint4*)(A + (size_t)(m0+r)*lda + k0 + q*8);
            *(uint4*)(As + ((r>>4)<<10) + (q<<8) + ((r&15)<<4)) = v;
        }
        {
            int r = tid >> 2, q = tid & 3;
            uint4 v = *(const uint4*)(B + (size_t)(n0+r)*ldb + k0 + q*8);
            *(uint4*)(Bs + ((r>>4)<<10) + (q<<8) + ((r&15)<<4)) = v;
        }
        __syncthreads();
        bf16x8 af[4], bfr[2];
        #pragma unroll
        for (int i = 0; i < 4; ++i) af[i]  = *(bf16x8*)(As + ((wm*4+i)<<10) + (lane<<4));
        #pragma unroll
        for (int j = 0; j < 2; ++j) bfr[j] = *(bf16x8*)(Bs + ((wn*2+j)<<10) + (lane<<4));
        #pragma unroll
        for (int i = 0; i < 4; ++i)
            #pragma unroll
            for (int j = 0; j < 2; ++j)
                acc[i][j] = __builtin_amdgcn_mfma_f32_16x16x32_bf16(af[i], bfr[j], acc[i][j], 0, 0, 0);
        __syncthreads();
    }
    int colf = lane & 15, rowq = lane >> 4;
    #pragma unroll
    for (int j = 0; j < 2; ++j) {
        int col = n0 + (wn*2+j)*16 + colf;
        float bv = bias ? bias[col] : 0.f;
        #pragma unroll
        for (int i = 0; i < 4; ++i) {
            #pragma unroll
            for (int reg = 0; reg < 4; ++reg) {
                int row = m0 + (wm*4+i)*16 + rowq*4 + reg;
                float v = acc[i][j][reg] + bv;
                if (obf) ((unsigned short*)Cp)[(size_t)row*ldc + col] = f2bf(v);
                else     ((float*)Cp)[(size_t)row*ldc + col] = v;
            }
        }
    }
}

// ---------------------------------------------------------------------------
// out_k: grid (128,4). rows i0..i0+8 of out[b][i][j] = w2.relu(hx_i+hy_j)
// ---------------------------------------------------------------------------
__global__ __launch_bounds__(256) void out_k(
    const float* __restrict__ hxy, const float* __restrict__ w2,
    float* __restrict__ out_g)
{
    __shared__ float s_hx[9*129], s_hy[NN*129], s_w2[NHID];
    int b = blockIdx.x, i0 = blockIdx.y * 9, tid = threadIdx.x;
    for (int i = tid; i < 9*NHID; i += 256) {
        int n = i >> 7, h = i & 127;
        s_hx[n*129+h] = hxy[(size_t)(b*NN+i0+n)*256 + h];
    }
    for (int i = tid; i < NN*NHID; i += 256) {
        int n = i >> 7, h = i & 127;
        s_hy[n*129+h] = hxy[(size_t)(b*NN+n)*256 + 128 + h];
    }
    if (tid < NHID) s_w2[tid] = w2[tid];
    __syncthreads();
    for (int idx = tid; idx < 9*NN; idx += 256) {
        int il = idx / NN, j = idx - il*NN;
        const float* px = &s_hx[il*129];
        const float* py = &s_hy[j*129];
        float s = 0.f;
        #pragma unroll 8
        for (int h = 0; h < NHID; ++h) s += s_w2[h] * fmaxf(px[h] + py[h], 0.f);
        out_g[(size_t)b*NN*NN + (i0+il)*NN + j] = s;
    }
}

// ---------------------------------------------------------------------------
// iter_k: grid 128. C = out - out^T, 3 assignment iters, final A row-softmax
// pre-scaled by sigmoid(att) -> A_g.
// ---------------------------------------------------------------------------
__global__ __launch_bounds__(256) void iter_k(
    const float* __restrict__ out_g, const float* __restrict__ att,
    const float* __restrict__ lr, float* __restrict__ A_g)
{
    __shared__ __align__(16) float s_out[NN*S40], s_C[NN*S40], s_logits[NN*S40], s_P[NN*S40];
    __shared__ float s_sg[NN];
    int b = blockIdx.x, tid = threadIdx.x;
    for (int idx = tid; idx < NN*NN; idx += 256) {
        int i = idx / NN, j = idx - i*NN;
        s_out[i*S40+j] = out_g[(size_t)b*NN*NN + idx];
        s_logits[i*S40+j] = 0.f;
    }
    if (tid < NN) s_sg[tid] = sigf(att[b*NN + tid]);
    float lr_abs = fabsf(lr[0]);
    __syncthreads();
    for (int idx = tid; idx < NN*NN; idx += 256) {
        int i = idx / NN, j = idx - i*NN;
        s_C[i*S40+j] = s_out[i*S40+j] - s_out[j*S40+i];
    }
    __syncthreads();
    for (int it = 0; it < 3; ++it) {
        if (tid < NN) {
            int i = tid;
            float mx = -1e30f;
            for (int l = 0; l < NN; ++l) mx = fmaxf(mx, s_logits[i*S40+l]);
            float sum = 0.f;
            for (int l = 0; l < NN; ++l) { float e = expf(s_logits[i*S40+l]-mx); s_P[i*S40+l] = e; sum += e; }
            float inv = 1.f/sum;
            for (int l = 0; l < NN; ++l) s_P[i*S40+l] *= inv;
        }
        __syncthreads();
        if (tid < NN) {
            int l = tid;
            float S = 0.f;
            for (int i = 0; i < NN; ++i) S += s_P[i*S40+l];
            float cum = 0.f;
            for (int i = 0; i < NN; ++i) {
                float p = s_P[i*S40+l];
                cum += p;
                s_P[i*S40+l] = S - 2.f*cum + p;
            }
        }
        __syncthreads();
        for (int idx = tid; idx < NN*NN; idx += 256) {
            int i = idx / NN, j = idx - i*NN;
            const f32x4* Pp = (const f32x4*)&s_P[i*S40];
            const f32x4* Cc = (const f32x4*)&s_C[j*S40];
            float g = 0.f;
            #pragma unroll
            for (int q = 0; q < 9; ++q) {
                f32x4 a = Pp[q], bb = Cc[q];
                g += a[0]*bb[0] + a[1]*bb[1] + a[2]*bb[2] + a[3]*bb[3];
            }
            s_logits[i*S40+j] -= lr_abs * g;
        }
        __syncthreads();
    }
    if (tid < NN) {
        int i = tid;
        float mx = -1e30f;
        for (int l = 0; l < NN; ++l) mx = fmaxf(mx, s_logits[i*S40+l]);
        float sum = 0.f;
        for (int l = 0; l < NN; ++l) { float e = expf(s_logits[i*S40+l]-mx); s_P[i*S40+l] = e; sum += e; }
        float inv = 1.f/sum;
        for (int l = 0; l < NN; ++l)
            A_g[(size_t)b*NN*NN + i*NN + l] = s_P[i*S40+l] * inv * s_sg[l];
    }
}

// ---------------------------------------------------------------------------
// xseq_k: grid (128,2). xseq[i][b][c] = sum_l A[b][i][l]*feats[b][l][c], bf16.
// ---------------------------------------------------------------------------
__global__ __launch_bounds__(256) void xseq_k(
    const float* __restrict__ feats, const float* __restrict__ A_g,
    unsigned short* __restrict__ xseq)
{
    __shared__ float s_P[NN*S37];
    int b = blockIdx.x, half = blockIdx.y, tid = threadIdx.x;
    for (int idx = tid; idx < NN*NN; idx += 256) {
        int i = idx / NN, l = idx - i*NN;
        s_P[i*S37+l] = A_g[(size_t)b*NN*NN + idx];
    }
    __syncthreads();
    const float* fb = feats + (size_t)b*NN*NMID;
    int ncols = (half == 0 && tid < 32) ? 2 : 1;
    #pragma unroll
    for (int rep = 0; rep < 2; ++rep) {
        if (rep >= ncols) break;
        int c = (rep == 0) ? half*256 + tid : 512 + tid;
        float colv[NN];
        #pragma unroll
        for (int l = 0; l < NN; ++l) colv[l] = (c < NMID) ? fb[l*NMID + c] : 0.f;
        #pragma unroll 4
        for (int i = 0; i < NN; ++i) {
            float s = 0.f;
            #pragma unroll
            for (int l = 0; l < NN; ++l) s += s_P[i*S37+l] * colv[l];
            xseq[((size_t)i*NB + b)*KP + c] = f2bf(s);
        }
    }
}

// ---------------------------------------------------------------------------
// lstm_persist: ALL 36 LSTM steps in ONE dispatch — PIPELINED chunk waits,
// NO full barrier. (unchanged from r7 — 374us, 10.4us/step)
// MFMA iteration it consumes h column block kc = it*4+q, produced by block
// ct' = kc. Chunk c (its 8c..8c+7) needs ONLY producers 32c..32c+31 ->
// per-chunk flag waits; a block publishes after its h stores drain and
// proceeds immediately. Visibility latency pipelines under other chunks'
// compute.
// ---------------------------------------------------------------------------
__global__ __launch_bounds__(256, 2) void lstm_persist(
    const unsigned short* __restrict__ whh, const unsigned short* __restrict__ xw,
    unsigned short* __restrict__ hseq, float* __restrict__ dout,
    unsigned int* __restrict__ bar)
{
    __shared__ __align__(16) char Bls[65536];    // [kc 0..127][n' 0..31][16B]
    __shared__ __align__(16) float gates[32][36];
    int tid = threadIdx.x, lane = tid & 63, wave = tid >> 6;
    int bt = blockIdx.x >> 7, ct = blockIdx.x & 127;
    int m0 = bt * 32, n0 = ct * 32;
    // stage whh slice ONCE: 16 passes; each wave reads 1KB contiguous/row
    #pragma unroll
    for (int r = 0; r < 16; ++r) {
        int idx = r*256 + tid;
        int n = idx >> 7, kc = idx & 127;
        uint4 v = *(const uint4*)(whh + (size_t)(n0+n)*NOUT + kc*8);
        *(uint4*)(Bls + kc*512 + (((n&16) | ((n^kc)&15))<<4)) = v;
    }
    int wm = wave >> 1, wn = wave & 1;
    int q = lane >> 4, ml = lane & 15;
    int nl = wn*16 + ml;
    int ul = tid & 7, bl = tid >> 3;
    int b = m0 + bl, u = ct*8 + ul;
    unsigned int* flags = bar + bt*128;          // this group's 128 flags
    int fidx = lane & 31;                        // lane's flag slot in a chunk
    float cc = 0.f;
    __syncthreads();
    for (int t = 0; t < NN; ++t) {
        // xw contribution (includes b_ih+b_hh from the xw GEMM epilogue)
        uint2 xw2 = *(const uint2*)(xw + ((size_t)t*NB + b)*4*NOUT + n0 + ul*4);
        float g0 = bf2f((unsigned short)(xw2.x & 0xffffu));
        float g1 = bf2f((unsigned short)(xw2.x >> 16));
        float g2 = bf2f((unsigned short)(xw2.y & 0xffffu));
        float g3 = bf2f((unsigned short)(xw2.y >> 16));
        if (t > 0) {
            const unsigned short* hrow = hseq + (size_t)(t-1)*NB*NOUT
                                       + (size_t)(m0 + wm*16 + ml)*NOUT + q*8;
            f32x4 acc = (f32x4){0.f,0.f,0.f,0.f};
            unsigned tgt = (unsigned)t;
            #pragma unroll
            for (int c = 0; c < 4; ++c) {
                // wait for producers 32c..32c+31 to have published h_{t-1}
                for (;;) {
                    unsigned f = __hip_atomic_load(flags + 32*c + fidx,
                                      __ATOMIC_RELAXED, __HIP_MEMORY_SCOPE_AGENT);
                    if (__all(f >= tgt)) break;
                    __builtin_amdgcn_s_sleep(1);
                }
                asm volatile("" ::: "memory");   // no load hoisting above spin
                #pragma unroll
                for (int it2 = 0; it2 < 8; ++it2) {
                    int it = c*8 + it2;
                    int kc = it*4 + q;
                    bf16x8 a = *(const bf16x8*)(hrow + it*32);
                    bf16x8 bb = *(const bf16x8*)(Bls + kc*512 + (((nl&16) | ((nl^kc)&15))<<4));
                    acc = __builtin_amdgcn_mfma_f32_16x16x32_bf16(a, bb, acc, 0, 0, 0);
                }
            }
            #pragma unroll
            for (int reg = 0; reg < 4; ++reg)
                gates[wm*16 + q*4 + reg][wn*16 + ml] = acc[reg];
            __syncthreads();
            float4 gl = *(const float4*)&gates[bl][ul*4];
            g0 += gl.x; g1 += gl.y; g2 += gl.z; g3 += gl.w;
        }
        float ig = sigf(g0), fg = sigf(g1), gg = tanhf(g2), og = sigf(g3);
        cc = fg*cc + ig*gg;
        if (t == NN-1) {
            dout[(size_t)b*NOUT + u] = cc;
        } else {
            // lane-pair pack -> native 32-bit sc1 write-through store
            unsigned short hb = f2bf(og*tanhf(cc));
            unsigned partner = (unsigned)__shfl_down((int)(unsigned)hb, 1);
            if ((ul & 1) == 0) {
                unsigned word = (unsigned)hb | (partner << 16);
                unsigned* dst = (unsigned*)(hseq + (size_t)t*NB*NOUT
                                            + (size_t)b*NOUT + u);
                __hip_atomic_store(dst, word, __ATOMIC_RELAXED,
                                   __HIP_MEMORY_SCOPE_AGENT);
            }
            asm volatile("s_waitcnt vmcnt(0)" ::: "memory"); // h at coherent point
            __syncthreads();            // all threads drained + gates reads done
            if (tid == 0)
                __hip_atomic_store(flags + ct, (unsigned)(t + 1),
                                   __ATOMIC_RELAXED, __HIP_MEMORY_SCOPE_AGENT);
            // NO wait here — next step's chunk waits pipeline the latency
        }
    }
}

// ---------------------------------------------------------------------------
extern "C" void kernel_launch(void* const* d_in, const int* in_sizes, int n_in,
                              void* d_out, int out_size, void* d_ws, size_t ws_size,
                              hipStream_t stream) {
    (void)in_sizes; (void)n_in; (void)out_size; (void)ws_size;
    const float* boxes     = (const float*)d_in[0];
    const float* attention = (const float*)d_in[1];
    const float* features  = (const float*)d_in[2];
    const float* conv_w    = (const float*)d_in[3];
    const float* conv_b    = (const float*)d_in[4];
    const float* skew_wx   = (const float*)d_in[5];
    const float* skew_wy   = (const float*)d_in[6];
    const float* skew_b1   = (const float*)d_in[7];
    const float* skew_w2   = (const float*)d_in[8];
    // d_in[9] = skew_b2: cancels in C = out - out^T
    const float* w_ih      = (const float*)d_in[10];
    const float* w_hh      = (const float*)d_in[11];
    const float* b_ih      = (const float*)d_in[12];
    const float* b_hh      = (const float*)d_in[13];
    const float* lr        = (const float*)d_in[14];

    // workspace layout (bytes, 256-aligned). xw_bf in region 0 (the conv
    // split-K partials are gone). hseq aliases features_bf's region —
    // features_bf dead after conv64, hseq used only in the LSTM.
    char* ws = (char*)d_ws;
    unsigned short* xw_bf    = (unsigned short*)(ws);             // 4608x4096 bf16 37,748,736
    unsigned short* features_bf = (unsigned short*)(ws + 37748736); // 18,874,368
    unsigned short* hseq     = (unsigned short*)(ws + 37748736);  //  9,437,184 (aliases features_bf)
    unsigned short* convw_bf = (unsigned short*)(ws + 56623104);  //  2,097,152
    float*          feats    = (float*)(ws + 58720256);           //  9,529,344
    float*          hxy      = (float*)(ws + 68249600);           //  4,718,592
    unsigned short* feats_bf = (unsigned short*)(ws + 72968192);  //  5,013,504
    unsigned short* xseq_bf  = (unsigned short*)(ws + 77981696);  //  5,013,504
    unsigned short* wih_il   = (unsigned short*)(ws + 82995200);  //  4,456,448
    unsigned short* whh_il   = (unsigned short*)(ws + 87451648);  //  8,388,608
    unsigned short* wxy_bf   = (unsigned short*)(ws + 95840256);  //    278,528
    float*          comb_b   = (float*)(ws + 96118784);           //     16,384
    float*          hxy_b    = (float*)(ws + 96135168);           //      1,024
    float*          out_g    = (float*)(ws + 96660480);           //    663,552
    float*          A_g      = (float*)(ws + 97324032);           //    663,552
    unsigned int*   bar      = (unsigned int*)(ws + 97987584);    //      2,048 (4x128 flags)

    prep_all<<<2048, 256, 0, stream>>>(boxes, attention, features, conv_w,
                                       skew_wx, skew_wy, skew_b1, w_ih, w_hh,
                                       b_ih, b_hh, features_bf, convw_bf,
                                       wxy_bf, hxy_b, wih_il, whh_il, comb_b,
                                       bar, feats, feats_bf);
    // fused conv GEMM: no split-K, writes feats + feats_bf directly
    conv64<<<dim3(8, 72), 256, 0, stream>>>(features_bf, convw_bf, conv_b,
                                            feats, feats_bf);
    // hxy = feats . [wx;wy]^T + [b1;0]
    gemm_mfma<<<dim3(4, 36), 256, 0, stream>>>(feats_bf, wxy_bf, hxy_b,
                                               (void*)hxy, KP, KP, KP, 256, 0);
    // assignment pipeline
    out_k<<<dim3(NB, 4), 256, 0, stream>>>(hxy, skew_w2, out_g);
    iter_k<<<NB, 256, 0, stream>>>(out_g, attention, lr, A_g);
    xseq_k<<<dim3(NB, 2), 256, 0, stream>>>(feats, A_g, xseq_bf);
    // xw = xseq . w_ih_il^T + (b_ih+b_hh) -> bf16, 128x128 tiles, 1152 blocks
    gemm128<<<dim3(32, 36, 1), 256, 0, stream>>>(xseq_bf, wih_il, comb_b,
                                                 (void*)xw_bf, KP, KP, KP, 4*NOUT, 1, 0);
    // ALL 36 LSTM steps in one persistent dispatch (pipelined chunk waits)
    lstm_persist<<<512, 256, 0, stream>>>(whh_il, xw_bf, hseq,
                                          (float*)d_out, bar);
}

// Round 9
// 648.867 us; speedup vs baseline: 1.0258x; 1.0258x over previous
//
#include <hip/hip_runtime.h>
#include <math.h>

// Problem dims
#define NB 128
#define NN 36
#define S37 37            // padded stride (xseq_k)
#define S40 40            // padded stride, 16B-aligned rows (iter_k)
#define NFEAT 2048
#define NMID 517
#define KP 544            // padded K (multiple of 32) for MID-dim GEMMs
#define NHID 128
#define NOUT 1024
#define ROWS (NB*NN)      // 4608

typedef __bf16 bf16x8 __attribute__((ext_vector_type(8)));
typedef float  f32x4  __attribute__((ext_vector_type(4)));

__device__ __forceinline__ float sigf(float x){ return 1.f/(1.f+expf(-x)); }
__device__ __forceinline__ unsigned short f2bf(float x){
    unsigned u = __float_as_uint(x);
    return (unsigned short)((u + 0x7FFFu + ((u>>16)&1u)) >> 16);
}
__device__ __forceinline__ float bf2f(unsigned short b){
    return __uint_as_float(((unsigned)b) << 16);
}

// ---------------------------------------------------------------------------
// prep_all: ALL input casts/reorders/zeroing in one dispatch.
// ---------------------------------------------------------------------------
__global__ __launch_bounds__(256) void prep_all(
    const float* __restrict__ boxes, const float* __restrict__ att,
    const float* __restrict__ features, const float* __restrict__ conv_w,
    const float* __restrict__ wx, const float* __restrict__ wy,
    const float* __restrict__ b1, const float* __restrict__ w_ih,
    const float* __restrict__ w_hh, const float* __restrict__ b_ih,
    const float* __restrict__ b_hh,
    unsigned short* __restrict__ features_bf, unsigned short* __restrict__ convw_bf,
    unsigned short* __restrict__ wxy_bf, float* __restrict__ hxy_b,
    unsigned short* __restrict__ wih_il, unsigned short* __restrict__ whh_il,
    float* __restrict__ comb_b, unsigned int* __restrict__ bar,
    float* __restrict__ feats)
{
    int gtid = blockIdx.x*256 + threadIdx.x;
    int gs = gridDim.x*256;
    if (gtid < 128*64) {
        int b = gtid >> 6, t = gtid & 63;
        float mx = -1e30f;
        for (int idx = t; idx < 4*NN; idx += 64) mx = fmaxf(mx, boxes[b*4*NN + idx]);
        for (int off = 32; off > 0; off >>= 1) mx = fmaxf(mx, __shfl_down(mx, off));
        mx = __shfl(mx, 0);
        float inv = 1.f / mx;
        for (int idx = t; idx < 4*NN; idx += 64) {
            int r = idx / NN, n = idx - r*NN;
            feats[(size_t)(b*NN+n)*NMID + r] = boxes[b*4*NN + idx] * inv;
        }
        if (t < NN) feats[(size_t)(b*NN+t)*NMID + 4] = att[b*NN + t];
    }
    for (int i = gtid; i < ROWS*NFEAT; i += gs) features_bf[i] = f2bf(features[i]);
    for (int i = gtid; i < 512*NFEAT; i += gs) convw_bf[i] = f2bf(conv_w[i]);
    for (int i = gtid; i < 256*KP; i += gs) {
        int r = i / KP, k = i - r*KP;
        float v = 0.f;
        if (k < NMID) v = (r < NHID) ? wx[(size_t)r*NMID+k] : wy[(size_t)(r-NHID)*NMID+k];
        wxy_bf[i] = f2bf(v);
    }
    for (int i = gtid; i < 256; i += gs) hxy_b[i] = (i < NHID) ? b1[i] : 0.f;
    for (int i = gtid; i < 4*NOUT*KP; i += gs) {
        int row = i / KP, k = i - row*KP;
        int u = row >> 2, g = row & 3;
        wih_il[i] = (k < NMID) ? f2bf(w_ih[(size_t)(g*NOUT+u)*NMID + k]) : (unsigned short)0;
    }
    for (int i = gtid; i < 4*NOUT*NOUT; i += gs) {
        int row = i >> 10, k = i & 1023;
        int u = row >> 2, g = row & 3;
        whh_il[i] = f2bf(w_hh[(size_t)(g*NOUT+u)*NOUT + k]);
    }
    for (int i = gtid; i < 4*NOUT; i += gs) {
        int u = i >> 2, g = i & 3;
        comb_b[i] = b_ih[g*NOUT+u] + b_hh[g*NOUT+u];
    }
    // persistent-LSTM producer flags: 4 bt-groups x 128 blocks, monotonic epoch
    for (int i = gtid; i < 512; i += gs) bar[i] = 0u;
}

// ---------------------------------------------------------------------------
// gemm128: C[m,n] = sum_k A[m,k]*B[n,k] (+ bias). Block tile 128x128,
// 4 waves = 2x2, wave tile 64x64 (16 MFMA / 8 ds_read_b128 per iter).
// XOR-swizzled LDS (r' = r ^ (q<<2)) -> conflict-free stores AND reads.
// Optional split-K via blockIdx.z: kbeg = z*Ksl, f32 partial out at
// Cp + z*pstride (bias ignored when pstride > 0 path uses obf=0,bias=null).
// ---------------------------------------------------------------------------
__global__ __launch_bounds__(256) void gemm128(
    const unsigned short* __restrict__ A, const unsigned short* __restrict__ B,
    const float* __restrict__ bias, void* __restrict__ Cp,
    int Ksl, int lda, int ldb, int ldc, int obf, long long pstride)
{
    __shared__ __align__(16) char As[16384];
    __shared__ __align__(16) char Bs[16384];
    int m0 = blockIdx.y * 128, n0 = blockIdx.x * 128;
    int kbeg = blockIdx.z * Ksl;
    int tid = threadIdx.x;
    int lane = tid & 63, wave = tid >> 6;
    int wm = wave >> 1, wn = wave & 1;
    int sw = ((lane>>4)<<8) + (((lane&15) ^ ((lane>>4)<<2))<<4);
    f32x4 acc[4][4];
    #pragma unroll
    for (int i = 0; i < 4; ++i)
        #pragma unroll
        for (int j = 0; j < 4; ++j) acc[i][j] = (f32x4){0.f,0.f,0.f,0.f};

    for (int k0 = 0; k0 < Ksl; k0 += 32) {
        #pragma unroll
        for (int p = 0; p < 2; ++p) {
            int cc = p*256 + tid;
            int r = cc >> 2, q = cc & 3;
            int sa = ((r>>4)<<10) + (q<<8) + ((((r&15) ^ (q<<2)))<<4);
            uint4 va = *(const uint4*)(A + (size_t)(m0+r)*lda + kbeg + k0 + q*8);
            *(uint4*)(As + sa) = va;
            uint4 vb = *(const uint4*)(B + (size_t)(n0+r)*ldb + kbeg + k0 + q*8);
            *(uint4*)(Bs + sa) = vb;
        }
        __syncthreads();
        bf16x8 af[4], bfr[4];
        #pragma unroll
        for (int i = 0; i < 4; ++i) af[i]  = *(bf16x8*)(As + ((wm*4+i)<<10) + sw);
        #pragma unroll
        for (int j = 0; j < 4; ++j) bfr[j] = *(bf16x8*)(Bs + ((wn*4+j)<<10) + sw);
        #pragma unroll
        for (int i = 0; i < 4; ++i)
            #pragma unroll
            for (int j = 0; j < 4; ++j)
                acc[i][j] = __builtin_amdgcn_mfma_f32_16x16x32_bf16(af[i], bfr[j], acc[i][j], 0, 0, 0);
        __syncthreads();
    }
    int colf = lane & 15, rowq = lane >> 4;
    #pragma unroll
    for (int j = 0; j < 4; ++j) {
        int col = n0 + (wn*4+j)*16 + colf;
        float bv = bias ? bias[col] : 0.f;
        #pragma unroll
        for (int i = 0; i < 4; ++i) {
            #pragma unroll
            for (int reg = 0; reg < 4; ++reg) {
                int row = m0 + (wm*4+i)*16 + rowq*4 + reg;
                float v = acc[i][j][reg] + bv;
                if (obf) ((unsigned short*)Cp)[(size_t)row*ldc + col] = f2bf(v);
                else ((float*)Cp + (size_t)blockIdx.z*pstride)[(size_t)row*ldc + col] = v;
            }
        }
    }
}

// ---------------------------------------------------------------------------
// conv_reduce: feats[:,5:] = sum_z part[z] + conv_b; emits full padded bf16
// feats (cols 0..4 from feats, 5..516 computed, 517..543 zero).
// ---------------------------------------------------------------------------
__global__ __launch_bounds__(256) void conv_reduce(
    const float* __restrict__ part, const float* __restrict__ bias,
    float* __restrict__ feats, unsigned short* __restrict__ feats_bf)
{
    int gtid = blockIdx.x*256 + threadIdx.x;
    int gs = gridDim.x*256;
    const size_t PS = (size_t)ROWS * 512;
    for (int i = gtid; i < ROWS*512; i += gs) {
        int r = i >> 9, cc = i & 511;
        float s = part[i] + part[PS+i] + part[2*PS+i] + part[3*PS+i] + bias[cc];
        feats[(size_t)r*NMID + 5 + cc] = s;
        feats_bf[(size_t)r*KP + 5 + cc] = f2bf(s);
    }
    for (int i = gtid; i < ROWS*5; i += gs) {
        int r = i / 5, cc = i - r*5;
        feats_bf[(size_t)r*KP + cc] = f2bf(feats[(size_t)r*NMID + cc]);
    }
    for (int i = gtid; i < ROWS*27; i += gs) {
        int r = i / 27, cc = i - r*27;
        feats_bf[(size_t)r*KP + 517 + cc] = 0;
    }
}

// ---------------------------------------------------------------------------
// bf16 MFMA GEMM (hxy only): tile 128x64, wave tile 64x32.
// ---------------------------------------------------------------------------
__global__ __launch_bounds__(256) void gemm_mfma(
    const unsigned short* __restrict__ A, const unsigned short* __restrict__ B,
    const float* __restrict__ bias, void* __restrict__ Cp,
    int K, int lda, int ldb, int ldc, int obf)
{
    __shared__ __align__(16) char As[8192];
    __shared__ __align__(16) char Bs[4096];
    int m0 = blockIdx.y * 128, n0 = blockIdx.x * 64;
    int tid = threadIdx.x;
    int lane = tid & 63, wave = tid >> 6;
    int wm = wave >> 1, wn = wave & 1;
    f32x4 acc[4][2];
    #pragma unroll
    for (int i = 0; i < 4; ++i)
        #pragma unroll
        for (int j = 0; j < 2; ++j) acc[i][j] = (f32x4){0.f,0.f,0.f,0.f};

    for (int k0 = 0; k0 < K; k0 += 32) {
        #pragma unroll
        for (int cc = tid; cc < 512; cc += 256) {
            int r = cc >> 2, q = cc & 3;
            uint4 v = *(const uint4*)(A + (size_t)(m0+r)*lda + k0 + q*8);
            *(uint4*)(As + ((r>>4)<<10) + (q<<8) + ((r&15)<<4)) = v;
        }
        {
            int r = tid >> 2, q = tid & 3;
            uint4 v = *(const uint4*)(B + (size_t)(n0+r)*ldb + k0 + q*8);
            *(uint4*)(Bs + ((r>>4)<<10) + (q<<8) + ((r&15)<<4)) = v;
        }
        __syncthreads();
        bf16x8 af[4], bfr[2];
        #pragma unroll
        for (int i = 0; i < 4; ++i) af[i]  = *(bf16x8*)(As + ((wm*4+i)<<10) + (lane<<4));
        #pragma unroll
        for (int j = 0; j < 2; ++j) bfr[j] = *(bf16x8*)(Bs + ((wn*2+j)<<10) + (lane<<4));
        #pragma unroll
        for (int i = 0; i < 4; ++i)
            #pragma unroll
            for (int j = 0; j < 2; ++j)
                acc[i][j] = __builtin_amdgcn_mfma_f32_16x16x32_bf16(af[i], bfr[j], acc[i][j], 0, 0, 0);
        __syncthreads();
    }
    int colf = lane & 15, rowq = lane >> 4;
    #pragma unroll
    for (int j = 0; j < 2; ++j) {
        int col = n0 + (wn*2+j)*16 + colf;
        float bv = bias ? bias[col] : 0.f;
        #pragma unroll
        for (int i = 0; i < 4; ++i) {
            #pragma unroll
            for (int reg = 0; reg < 4; ++reg) {
                int row = m0 + (wm*4+i)*16 + rowq*4 + reg;
                float v = acc[i][j][reg] + bv;
                if (obf) ((unsigned short*)Cp)[(size_t)row*ldc + col] = f2bf(v);
                else     ((float*)Cp)[(size_t)row*ldc + col] = v;
            }
        }
    }
}

// ---------------------------------------------------------------------------
// out_k: grid (128,4). rows i0..i0+8 of out[b][i][j] = w2.relu(hx_i+hy_j)
// ---------------------------------------------------------------------------
__global__ __launch_bounds__(256) void out_k(
    const float* __restrict__ hxy, const float* __restrict__ w2,
    float* __restrict__ out_g)
{
    __shared__ float s_hx[9*129], s_hy[NN*129], s_w2[NHID];
    int b = blockIdx.x, i0 = blockIdx.y * 9, tid = threadIdx.x;
    for (int i = tid; i < 9*NHID; i += 256) {
        int n = i >> 7, h = i & 127;
        s_hx[n*129+h] = hxy[(size_t)(b*NN+i0+n)*256 + h];
    }
    for (int i = tid; i < NN*NHID; i += 256) {
        int n = i >> 7, h = i & 127;
        s_hy[n*129+h] = hxy[(size_t)(b*NN+n)*256 + 128 + h];
    }
    if (tid < NHID) s_w2[tid] = w2[tid];
    __syncthreads();
    for (int idx = tid; idx < 9*NN; idx += 256) {
        int il = idx / NN, j = idx - il*NN;
        const float* px = &s_hx[il*129];
        const float* py = &s_hy[j*129];
        float s = 0.f;
        #pragma unroll 8
        for (int h = 0; h < NHID; ++h) s += s_w2[h] * fmaxf(px[h] + py[h], 0.f);
        out_g[(size_t)b*NN*NN + (i0+il)*NN + j] = s;
    }
}

// ---------------------------------------------------------------------------
// iter_k: grid 128. C = out - out^T, 3 assignment iters, final A row-softmax
// pre-scaled by sigmoid(att) -> A_g.
// ---------------------------------------------------------------------------
__global__ __launch_bounds__(256) void iter_k(
    const float* __restrict__ out_g, const float* __restrict__ att,
    const float* __restrict__ lr, float* __restrict__ A_g)
{
    __shared__ __align__(16) float s_out[NN*S40], s_C[NN*S40], s_logits[NN*S40], s_P[NN*S40];
    __shared__ float s_sg[NN];
    int b = blockIdx.x, tid = threadIdx.x;
    for (int idx = tid; idx < NN*NN; idx += 256) {
        int i = idx / NN, j = idx - i*NN;
        s_out[i*S40+j] = out_g[(size_t)b*NN*NN + idx];
        s_logits[i*S40+j] = 0.f;
    }
    if (tid < NN) s_sg[tid] = sigf(att[b*NN + tid]);
    float lr_abs = fabsf(lr[0]);
    __syncthreads();
    for (int idx = tid; idx < NN*NN; idx += 256) {
        int i = idx / NN, j = idx - i*NN;
        s_C[i*S40+j] = s_out[i*S40+j] - s_out[j*S40+i];
    }
    __syncthreads();
    for (int it = 0; it < 3; ++it) {
        if (tid < NN) {
            int i = tid;
            float mx = -1e30f;
            for (int l = 0; l < NN; ++l) mx = fmaxf(mx, s_logits[i*S40+l]);
            float sum = 0.f;
            for (int l = 0; l < NN; ++l) { float e = expf(s_logits[i*S40+l]-mx); s_P[i*S40+l] = e; sum += e; }
            float inv = 1.f/sum;
            for (int l = 0; l < NN; ++l) s_P[i*S40+l] *= inv;
        }
        __syncthreads();
        if (tid < NN) {
            int l = tid;
            float S = 0.f;
            for (int i = 0; i < NN; ++i) S += s_P[i*S40+l];
            float cum = 0.f;
            for (int i = 0; i < NN; ++i) {
                float p = s_P[i*S40+l];
                cum += p;
                s_P[i*S40+l] = S - 2.f*cum + p;
            }
        }
        __syncthreads();
        for (int idx = tid; idx < NN*NN; idx += 256) {
            int i = idx / NN, j = idx - i*NN;
            const f32x4* Pp = (const f32x4*)&s_P[i*S40];
            const f32x4* Cc = (const f32x4*)&s_C[j*S40];
            float g = 0.f;
            #pragma unroll
            for (int q = 0; q < 9; ++q) {
                f32x4 a = Pp[q], bb = Cc[q];
                g += a[0]*bb[0] + a[1]*bb[1] + a[2]*bb[2] + a[3]*bb[3];
            }
            s_logits[i*S40+j] -= lr_abs * g;
        }
        __syncthreads();
    }
    if (tid < NN) {
        int i = tid;
        float mx = -1e30f;
        for (int l = 0; l < NN; ++l) mx = fmaxf(mx, s_logits[i*S40+l]);
        float sum = 0.f;
        for (int l = 0; l < NN; ++l) { float e = expf(s_logits[i*S40+l]-mx); s_P[i*S40+l] = e; sum += e; }
        float inv = 1.f/sum;
        for (int l = 0; l < NN; ++l)
            A_g[(size_t)b*NN*NN + i*NN + l] = s_P[i*S40+l] * inv * s_sg[l];
    }
}

// ---------------------------------------------------------------------------
// xseq_k: grid (128,2). xseq[i][b][c] = sum_l A[b][i][l]*feats[b][l][c], bf16.
// ---------------------------------------------------------------------------
__global__ __launch_bounds__(256) void xseq_k(
    const float* __restrict__ feats, const float* __restrict__ A_g,
    unsigned short* __restrict__ xseq)
{
    __shared__ float s_P[NN*S37];
    int b = blockIdx.x, half = blockIdx.y, tid = threadIdx.x;
    for (int idx = tid; idx < NN*NN; idx += 256) {
        int i = idx / NN, l = idx - i*NN;
        s_P[i*S37+l] = A_g[(size_t)b*NN*NN + idx];
    }
    __syncthreads();
    const float* fb = feats + (size_t)b*NN*NMID;
    int ncols = (half == 0 && tid < 32) ? 2 : 1;
    #pragma unroll
    for (int rep = 0; rep < 2; ++rep) {
        if (rep >= ncols) break;
        int c = (rep == 0) ? half*256 + tid : 512 + tid;
        float colv[NN];
        #pragma unroll
        for (int l = 0; l < NN; ++l) colv[l] = (c < NMID) ? fb[l*NMID + c] : 0.f;
        #pragma unroll 4
        for (int i = 0; i < NN; ++i) {
            float s = 0.f;
            #pragma unroll
            for (int l = 0; l < NN; ++l) s += s_P[i*S37+l] * colv[l];
            xseq[((size_t)i*NB + b)*KP + c] = f2bf(s);
        }
    }
}

// ---------------------------------------------------------------------------
// lstm_persist: ALL 36 LSTM steps in ONE dispatch — pipelined chunk waits
// + DOUBLE-BUFFERED h loads (new vs r7).
// r7's chunk loop exposed each chunk's ~600-900cy L3 h-load latency: loads
// couldn't issue until the chunk's flags confirmed, and the MFMAs sat right
// behind the waitcnt. New schedule per step:
//   wait(0); issue loads(0)
//   for c: { if c<3: wait(c+1); issue loads(c+1) }  // loads(c) fly in spin
//            MFMA(c)                                // loads(c+1) fly in MFMA
// abuf[2][8] indexed only by unrolled constants (stays in VGPRs).
// Everything else identical to r7 (646us best-known):
//  - per-chunk producer flags: MFMA iter it consumes h col block kc=it*4+q,
//    produced by block ct'=kc -> chunk c needs only producers 32c..32c+31.
//  - publish: sc1 h stores drained (vmcnt 0) -> __syncthreads -> tid0 flag
//    store; block proceeds immediately (no step-end wait).
//  - h transport: fresh hseq[t]/step, lane-pair-packed 32-bit sc1 stores.
// ---------------------------------------------------------------------------
__global__ __launch_bounds__(256, 2) void lstm_persist(
    const unsigned short* __restrict__ whh, const unsigned short* __restrict__ xw,
    unsigned short* __restrict__ hseq, float* __restrict__ dout,
    unsigned int* __restrict__ bar)
{
    __shared__ __align__(16) char Bls[65536];    // [kc 0..127][n' 0..31][16B]
    __shared__ __align__(16) float gates[32][36];
    int tid = threadIdx.x, lane = tid & 63, wave = tid >> 6;
    int bt = blockIdx.x >> 7, ct = blockIdx.x & 127;
    int m0 = bt * 32, n0 = ct * 32;
    // stage whh slice ONCE: 16 passes; each wave reads 1KB contiguous/row
    #pragma unroll
    for (int r = 0; r < 16; ++r) {
        int idx = r*256 + tid;
        int n = idx >> 7, kc = idx & 127;
        uint4 v = *(const uint4*)(whh + (size_t)(n0+n)*NOUT + kc*8);
        *(uint4*)(Bls + kc*512 + (((n&16) | ((n^kc)&15))<<4)) = v;
    }
    int wm = wave >> 1, wn = wave & 1;
    int q = lane >> 4, ml = lane & 15;
    int nl = wn*16 + ml;
    int ul = tid & 7, bl = tid >> 3;
    int b = m0 + bl, u = ct*8 + ul;
    unsigned int* flags = bar + bt*128;          // this group's 128 flags
    int fidx = lane & 31;                        // lane's flag slot in a chunk
    float cc = 0.f;
    __syncthreads();
    for (int t = 0; t < NN; ++t) {
        // xw contribution (includes b_ih+b_hh from the xw GEMM epilogue)
        uint2 xw2 = *(const uint2*)(xw + ((size_t)t*NB + b)*4*NOUT + n0 + ul*4);
        float g0 = bf2f((unsigned short)(xw2.x & 0xffffu));
        float g1 = bf2f((unsigned short)(xw2.x >> 16));
        float g2 = bf2f((unsigned short)(xw2.y & 0xffffu));
        float g3 = bf2f((unsigned short)(xw2.y >> 16));
        if (t > 0) {
            const unsigned short* hrow = hseq + (size_t)(t-1)*NB*NOUT
                                       + (size_t)(m0 + wm*16 + ml)*NOUT + q*8;
            f32x4 acc = (f32x4){0.f,0.f,0.f,0.f};
            unsigned tgt = (unsigned)t;
            bf16x8 abuf[2][8];
            // chunk 0: wait + issue loads
            for (;;) {
                unsigned f = __hip_atomic_load(flags + fidx,
                                  __ATOMIC_RELAXED, __HIP_MEMORY_SCOPE_AGENT);
                if (__all(f >= tgt)) break;
                __builtin_amdgcn_s_sleep(1);
            }
            asm volatile("" ::: "memory");   // no load hoisting above spin
            #pragma unroll
            for (int i = 0; i < 8; ++i)
                abuf[0][i] = *(const bf16x8*)(hrow + i*32);
            #pragma unroll
            for (int c = 0; c < 4; ++c) {
                if (c < 3) {
                    // wait for chunk c+1's producers; chunk c's loads fly
                    for (;;) {
                        unsigned f = __hip_atomic_load(flags + 32*(c+1) + fidx,
                                          __ATOMIC_RELAXED, __HIP_MEMORY_SCOPE_AGENT);
                        if (__all(f >= tgt)) break;
                        __builtin_amdgcn_s_sleep(1);
                    }
                    asm volatile("" ::: "memory");
                    #pragma unroll
                    for (int i = 0; i < 8; ++i)
                        abuf[(c+1)&1][i] = *(const bf16x8*)(hrow + ((c+1)*8 + i)*32);
                }
                // MFMA chunk c (loads(c+1) in flight behind these)
                #pragma unroll
                for (int it2 = 0; it2 < 8; ++it2) {
                    int kc = (c*8 + it2)*4 + q;
                    bf16x8 bb = *(const bf16x8*)(Bls + kc*512 + (((nl&16) | ((nl^kc)&15))<<4));
                    acc = __builtin_amdgcn_mfma_f32_16x16x32_bf16(abuf[c&1][it2], bb, acc, 0, 0, 0);
                }
            }
            #pragma unroll
            for (int reg = 0; reg < 4; ++reg)
                gates[wm*16 + q*4 + reg][wn*16 + ml] = acc[reg];
            __syncthreads();
            float4 gl = *(const float4*)&gates[bl][ul*4];
            g0 += gl.x; g1 += gl.y; g2 += gl.z; g3 += gl.w;
        }
        float ig = sigf(g0), fg = sigf(g1), gg = tanhf(g2), og = sigf(g3);
        cc = fg*cc + ig*gg;
        if (t == NN-1) {
            dout[(size_t)b*NOUT + u] = cc;
        } else {
            // lane-pair pack -> native 32-bit sc1 write-through store
            unsigned short hb = f2bf(og*tanhf(cc));
            unsigned partner = (unsigned)__shfl_down((int)(unsigned)hb, 1);
            if ((ul & 1) == 0) {
                unsigned word = (unsigned)hb | (partner << 16);
                unsigned* dst = (unsigned*)(hseq + (size_t)t*NB*NOUT
                                            + (size_t)b*NOUT + u);
                __hip_atomic_store(dst, word, __ATOMIC_RELAXED,
                                   __HIP_MEMORY_SCOPE_AGENT);
            }
            asm volatile("s_waitcnt vmcnt(0)" ::: "memory"); // h at coherent point
            __syncthreads();            // all threads drained + gates reads done
            if (tid == 0)
                __hip_atomic_store(flags + ct, (unsigned)(t + 1),
                                   __ATOMIC_RELAXED, __HIP_MEMORY_SCOPE_AGENT);
            // NO wait here — next step's chunk waits pipeline the latency
        }
    }
}

// ---------------------------------------------------------------------------
extern "C" void kernel_launch(void* const* d_in, const int* in_sizes, int n_in,
                              void* d_out, int out_size, void* d_ws, size_t ws_size,
                              hipStream_t stream) {
    (void)in_sizes; (void)n_in; (void)out_size; (void)ws_size;
    const float* boxes     = (const float*)d_in[0];
    const float* attention = (const float*)d_in[1];
    const float* features  = (const float*)d_in[2];
    const float* conv_w    = (const float*)d_in[3];
    const float* conv_b    = (const float*)d_in[4];
    const float* skew_wx   = (const float*)d_in[5];
    const float* skew_wy   = (const float*)d_in[6];
    const float* skew_b1   = (const float*)d_in[7];
    const float* skew_w2   = (const float*)d_in[8];
    // d_in[9] = skew_b2: cancels in C = out - out^T
    const float* w_ih      = (const float*)d_in[10];
    const float* w_hh      = (const float*)d_in[11];
    const float* b_ih      = (const float*)d_in[12];
    const float* b_hh      = (const float*)d_in[13];
    const float* lr        = (const float*)d_in[14];

    // workspace layout (bytes, 256-aligned). part (conv split-K partials)
    // and xw_bf share region 0 — partials dead before the xw GEMM writes.
    // hseq (36-step h buffers, 9.4MB) aliases features_bf's region —
    // features_bf is dead after the conv GEMM, hseq used only in the LSTM;
    // inter-dispatch cache maintenance clears stale lines at kernel start.
    char* ws = (char*)d_ws;
    float*          part     = (float*)(ws);                      // 4x4608x512 f32  37,748,736
    unsigned short* xw_bf    = (unsigned short*)(ws);             // 4608x4096 bf16 (same region)
    unsigned short* features_bf = (unsigned short*)(ws + 37748736); // 18,874,368
    unsigned short* hseq     = (unsigned short*)(ws + 37748736);  //  9,437,184 (aliases features_bf)
    unsigned short* convw_bf = (unsigned short*)(ws + 56623104);  //  2,097,152
    float*          feats    = (float*)(ws + 58720256);           //  9,529,344
    float*          hxy      = (float*)(ws + 68249600);           //  4,718,592
    unsigned short* feats_bf = (unsigned short*)(ws + 72968192);  //  5,013,504
    unsigned short* xseq_bf  = (unsigned short*)(ws + 77981696);  //  5,013,504
    unsigned short* wih_il   = (unsigned short*)(ws + 82995200);  //  4,456,448
    unsigned short* whh_il   = (unsigned short*)(ws + 87451648);  //  8,388,608
    unsigned short* wxy_bf   = (unsigned short*)(ws + 95840256);  //    278,528
    float*          comb_b   = (float*)(ws + 96118784);           //     16,384
    float*          hxy_b    = (float*)(ws + 96135168);           //      1,024
    float*          out_g    = (float*)(ws + 96660480);           //    663,552
    float*          A_g      = (float*)(ws + 97324032);           //    663,552
    unsigned int*   bar      = (unsigned int*)(ws + 97987584);    //      2,048 (4x128 flags)

    prep_all<<<2048, 256, 0, stream>>>(boxes, attention, features, conv_w,
                                       skew_wx, skew_wy, skew_b1, w_ih, w_hh,
                                       b_ih, b_hh, features_bf, convw_bf,
                                       wxy_bf, hxy_b, wih_il, whh_il, comb_b,
                                       bar, feats);
    // conv split-K: 128x128 tiles, K-slice 512, grid (4,36,4) = 576 blocks
    gemm128<<<dim3(4, 36, 4), 256, 0, stream>>>(features_bf, convw_bf, nullptr,
                                                (void*)part, 512, NFEAT, NFEAT, 512, 0,
                                                (long long)ROWS*512);
    conv_reduce<<<2048, 256, 0, stream>>>(part, conv_b, feats, feats_bf);
    // hxy = feats . [wx;wy]^T + [b1;0]
    gemm_mfma<<<dim3(4, 36), 256, 0, stream>>>(feats_bf, wxy_bf, hxy_b,
                                               (void*)hxy, KP, KP, KP, 256, 0);
    // assignment pipeline
    out_k<<<dim3(NB, 4), 256, 0, stream>>>(hxy, skew_w2, out_g);
    iter_k<<<NB, 256, 0, stream>>>(out_g, attention, lr, A_g);
    xseq_k<<<dim3(NB, 2), 256, 0, stream>>>(feats, A_g, xseq_bf);
    // xw = xseq . w_ih_il^T + (b_ih+b_hh) -> bf16, 128x128 tiles, 1152 blocks
    gemm128<<<dim3(32, 36, 1), 256, 0, stream>>>(xseq_bf, wih_il, comb_b,
                                                 (void*)xw_bf, KP, KP, KP, 4*NOUT, 1, 0);
    // ALL 36 LSTM steps in one persistent dispatch (pipelined chunk waits
    // + double-buffered h loads)
    lstm_persist<<<512, 256, 0, stream>>>(whh_il, xw_bf, hseq,
                                          (float*)d_out, bar);
}

// Round 10
// 644.094 us; speedup vs baseline: 1.0334x; 1.0074x over previous
//
#include <hip/hip_runtime.h>
#include <math.h>

// Problem dims
#define NB 128
#define NN 36
#define S37 37            // padded stride (xseq_k)
#define S40 40            // padded stride, 16B-aligned rows (iter_k)
#define NFEAT 2048
#define NMID 517
#define KP 544            // padded K (multiple of 32) for MID-dim GEMMs
#define NHID 128
#define NOUT 1024
#define ROWS (NB*NN)      // 4608

typedef __bf16 bf16x8 __attribute__((ext_vector_type(8)));
typedef float  f32x4  __attribute__((ext_vector_type(4)));

__device__ __forceinline__ float sigf(float x){ return 1.f/(1.f+expf(-x)); }
__device__ __forceinline__ unsigned short f2bf(float x){
    unsigned u = __float_as_uint(x);
    return (unsigned short)((u + 0x7FFFu + ((u>>16)&1u)) >> 16);
}
__device__ __forceinline__ float bf2f(unsigned short b){
    return __uint_as_float(((unsigned)b) << 16);
}
// async global->LDS, 16B/lane: LDS dest = wave-uniform base + lane*16
__device__ __forceinline__ void gload_lds16(const unsigned short* g, void* lds){
    __builtin_amdgcn_global_load_lds(
        (const __attribute__((address_space(1))) void*)g,
        (__attribute__((address_space(3))) void*)lds, 16, 0, 0);
}

// ---------------------------------------------------------------------------
// prep_all: ALL input casts/reorders/zeroing in one dispatch.
// ---------------------------------------------------------------------------
__global__ __launch_bounds__(256) void prep_all(
    const float* __restrict__ boxes, const float* __restrict__ att,
    const float* __restrict__ features, const float* __restrict__ conv_w,
    const float* __restrict__ wx, const float* __restrict__ wy,
    const float* __restrict__ b1, const float* __restrict__ w_ih,
    const float* __restrict__ w_hh, const float* __restrict__ b_ih,
    const float* __restrict__ b_hh,
    unsigned short* __restrict__ features_bf, unsigned short* __restrict__ convw_bf,
    unsigned short* __restrict__ wxy_bf, float* __restrict__ hxy_b,
    unsigned short* __restrict__ wih_il, unsigned short* __restrict__ whh_il,
    float* __restrict__ comb_b, unsigned int* __restrict__ bar,
    float* __restrict__ feats)
{
    int gtid = blockIdx.x*256 + threadIdx.x;
    int gs = gridDim.x*256;
    if (gtid < 128*64) {
        int b = gtid >> 6, t = gtid & 63;
        float mx = -1e30f;
        for (int idx = t; idx < 4*NN; idx += 64) mx = fmaxf(mx, boxes[b*4*NN + idx]);
        for (int off = 32; off > 0; off >>= 1) mx = fmaxf(mx, __shfl_down(mx, off));
        mx = __shfl(mx, 0);
        float inv = 1.f / mx;
        for (int idx = t; idx < 4*NN; idx += 64) {
            int r = idx / NN, n = idx - r*NN;
            feats[(size_t)(b*NN+n)*NMID + r] = boxes[b*4*NN + idx] * inv;
        }
        if (t < NN) feats[(size_t)(b*NN+t)*NMID + 4] = att[b*NN + t];
    }
    for (int i = gtid; i < ROWS*NFEAT; i += gs) features_bf[i] = f2bf(features[i]);
    for (int i = gtid; i < 512*NFEAT; i += gs) convw_bf[i] = f2bf(conv_w[i]);
    for (int i = gtid; i < 256*KP; i += gs) {
        int r = i / KP, k = i - r*KP;
        float v = 0.f;
        if (k < NMID) v = (r < NHID) ? wx[(size_t)r*NMID+k] : wy[(size_t)(r-NHID)*NMID+k];
        wxy_bf[i] = f2bf(v);
    }
    for (int i = gtid; i < 256; i += gs) hxy_b[i] = (i < NHID) ? b1[i] : 0.f;
    for (int i = gtid; i < 4*NOUT*KP; i += gs) {
        int row = i / KP, k = i - row*KP;
        int u = row >> 2, g = row & 3;
        wih_il[i] = (k < NMID) ? f2bf(w_ih[(size_t)(g*NOUT+u)*NMID + k]) : (unsigned short)0;
    }
    for (int i = gtid; i < 4*NOUT*NOUT; i += gs) {
        int row = i >> 10, k = i & 1023;
        int u = row >> 2, g = row & 3;
        whh_il[i] = f2bf(w_hh[(size_t)(g*NOUT+u)*NOUT + k]);
    }
    for (int i = gtid; i < 4*NOUT; i += gs) {
        int u = i >> 2, g = i & 3;
        comb_b[i] = b_ih[g*NOUT+u] + b_hh[g*NOUT+u];
    }
    // persistent-LSTM producer flags: 4 bt-groups x 128 blocks, monotonic epoch
    for (int i = gtid; i < 512; i += gs) bar[i] = 0u;
}

// ---------------------------------------------------------------------------
// gemm128: C[m,n] = sum_k A[m,k]*B[n,k] (+ bias). Block tile 128x128,
// 4 waves = 2x2, wave tile 64x64 (16 MFMA per iter).
// r9 profile: MfmaUtil 15%, VALUBusy 31% -> reg-staging VALU-bound.
// NEW: staging via global_load_lds width=16 (async, no VGPR round-trip).
// LDS layout unchanged (XOR-swizzled); gload_lds writes linearly
// (base+lane*16), so the SOURCE address is inverse-swizzled per lane:
// lane l=(q<<4)|sl stages row grp*16 + (sl^(q<<2)), chunk q -> byte-identical
// LDS contents, read path untouched (rule: swizzle both sides or neither).
// 16 groups of 1KB per k-iter (8 As + 8 Bs), 4 loads/wave.
// ---------------------------------------------------------------------------
__global__ __launch_bounds__(256) void gemm128(
    const unsigned short* __restrict__ A, const unsigned short* __restrict__ B,
    const float* __restrict__ bias, void* __restrict__ Cp,
    int Ksl, int lda, int ldb, int ldc, int obf, long long pstride)
{
    __shared__ __align__(16) char As[16384];
    __shared__ __align__(16) char Bs[16384];
    int m0 = blockIdx.y * 128, n0 = blockIdx.x * 128;
    int kbeg = blockIdx.z * Ksl;
    int tid = threadIdx.x;
    int lane = tid & 63, wave = tid >> 6;
    int wm = wave >> 1, wn = wave & 1;
    int sw = ((lane>>4)<<8) + (((lane&15) ^ ((lane>>4)<<2))<<4);
    f32x4 acc[4][4];
    #pragma unroll
    for (int i = 0; i < 4; ++i)
        #pragma unroll
        for (int j = 0; j < 4; ++j) acc[i][j] = (f32x4){0.f,0.f,0.f,0.f};

    // per-lane inverse-swizzled source rows for this wave's 2 groups
    int gq = lane >> 4, sl = lane & 15;
    int rloc = sl ^ (gq << 2);
    int g0r = wave*2*16 + rloc, g1r = g0r + 16;
    const unsigned short* a0 = A + (size_t)(m0 + g0r)*lda + kbeg + gq*8;
    const unsigned short* a1 = A + (size_t)(m0 + g1r)*lda + kbeg + gq*8;
    const unsigned short* b0 = B + (size_t)(n0 + g0r)*ldb + kbeg + gq*8;
    const unsigned short* b1 = B + (size_t)(n0 + g1r)*ldb + kbeg + gq*8;
    char* asd0 = As + ((wave*2)<<10); char* asd1 = asd0 + 1024;
    char* bsd0 = Bs + ((wave*2)<<10); char* bsd1 = bsd0 + 1024;

    for (int k0 = 0; k0 < Ksl; k0 += 32) {
        gload_lds16(a0 + k0, asd0);
        gload_lds16(a1 + k0, asd1);
        gload_lds16(b0 + k0, bsd0);
        gload_lds16(b1 + k0, bsd1);
        __syncthreads();   // compiler drains vmcnt before s_barrier
        bf16x8 af[4], bfr[4];
        #pragma unroll
        for (int i = 0; i < 4; ++i) af[i]  = *(bf16x8*)(As + ((wm*4+i)<<10) + sw);
        #pragma unroll
        for (int j = 0; j < 4; ++j) bfr[j] = *(bf16x8*)(Bs + ((wn*4+j)<<10) + sw);
        #pragma unroll
        for (int i = 0; i < 4; ++i)
            #pragma unroll
            for (int j = 0; j < 4; ++j)
                acc[i][j] = __builtin_amdgcn_mfma_f32_16x16x32_bf16(af[i], bfr[j], acc[i][j], 0, 0, 0);
        __syncthreads();
    }
    int colf = lane & 15, rowq = lane >> 4;
    #pragma unroll
    for (int j = 0; j < 4; ++j) {
        int col = n0 + (wn*4+j)*16 + colf;
        float bv = bias ? bias[col] : 0.f;
        #pragma unroll
        for (int i = 0; i < 4; ++i) {
            #pragma unroll
            for (int reg = 0; reg < 4; ++reg) {
                int row = m0 + (wm*4+i)*16 + rowq*4 + reg;
                float v = acc[i][j][reg] + bv;
                if (obf) ((unsigned short*)Cp)[(size_t)row*ldc + col] = f2bf(v);
                else ((float*)Cp + (size_t)blockIdx.z*pstride)[(size_t)row*ldc + col] = v;
            }
        }
    }
}

// ---------------------------------------------------------------------------
// conv_reduce: feats[:,5:] = sum_z part[z] + conv_b; emits full padded bf16
// feats (cols 0..4 from feats, 5..516 computed, 517..543 zero).
// ---------------------------------------------------------------------------
__global__ __launch_bounds__(256) void conv_reduce(
    const float* __restrict__ part, const float* __restrict__ bias,
    float* __restrict__ feats, unsigned short* __restrict__ feats_bf)
{
    int gtid = blockIdx.x*256 + threadIdx.x;
    int gs = gridDim.x*256;
    const size_t PS = (size_t)ROWS * 512;
    for (int i = gtid; i < ROWS*512; i += gs) {
        int r = i >> 9, cc = i & 511;
        float s = part[i] + part[PS+i] + part[2*PS+i] + part[3*PS+i] + bias[cc];
        feats[(size_t)r*NMID + 5 + cc] = s;
        feats_bf[(size_t)r*KP + 5 + cc] = f2bf(s);
    }
    for (int i = gtid; i < ROWS*5; i += gs) {
        int r = i / 5, cc = i - r*5;
        feats_bf[(size_t)r*KP + cc] = f2bf(feats[(size_t)r*NMID + cc]);
    }
    for (int i = gtid; i < ROWS*27; i += gs) {
        int r = i / 27, cc = i - r*27;
        feats_bf[(size_t)r*KP + 517 + cc] = 0;
    }
}

// ---------------------------------------------------------------------------
// bf16 MFMA GEMM (hxy only): tile 128x64, wave tile 64x32.
// Staging via global_load_lds width=16 (linear LDS layout, rloc = sl):
// 12 groups of 1KB per k-iter (8 As + 4 Bs), 3 loads/wave.
// ---------------------------------------------------------------------------
__global__ __launch_bounds__(256) void gemm_mfma(
    const unsigned short* __restrict__ A, const unsigned short* __restrict__ B,
    const float* __restrict__ bias, void* __restrict__ Cp,
    int K, int lda, int ldb, int ldc, int obf)
{
    __shared__ __align__(16) char As[8192];
    __shared__ __align__(16) char Bs[4096];
    int m0 = blockIdx.y * 128, n0 = blockIdx.x * 64;
    int tid = threadIdx.x;
    int lane = tid & 63, wave = tid >> 6;
    int wm = wave >> 1, wn = wave & 1;
    f32x4 acc[4][2];
    #pragma unroll
    for (int i = 0; i < 4; ++i)
        #pragma unroll
        for (int j = 0; j < 2; ++j) acc[i][j] = (f32x4){0.f,0.f,0.f,0.f};

    int gq = lane >> 4, sl = lane & 15;       // linear layout: rloc = sl
    int g0r = wave*2*16 + sl, g1r = g0r + 16;
    const unsigned short* a0 = A + (size_t)(m0 + g0r)*lda + gq*8;
    const unsigned short* a1 = A + (size_t)(m0 + g1r)*lda + gq*8;
    const unsigned short* bb0 = B + (size_t)(n0 + wave*16 + sl)*ldb + gq*8;
    char* asd0 = As + ((wave*2)<<10); char* asd1 = asd0 + 1024;
    char* bsd0 = Bs + (wave<<10);

    for (int k0 = 0; k0 < K; k0 += 32) {
        gload_lds16(a0 + k0, asd0);
        gload_lds16(a1 + k0, asd1);
        gload_lds16(bb0 + k0, bsd0);
        __syncthreads();
        bf16x8 af[4], bfr[2];
        #pragma unroll
        for (int i = 0; i < 4; ++i) af[i]  = *(bf16x8*)(As + ((wm*4+i)<<10) + (lane<<4));
        #pragma unroll
        for (int j = 0; j < 2; ++j) bfr[j] = *(bf16x8*)(Bs + ((wn*2+j)<<10) + (lane<<4));
        #pragma unroll
        for (int i = 0; i < 4; ++i)
            #pragma unroll
            for (int j = 0; j < 2; ++j)
                acc[i][j] = __builtin_amdgcn_mfma_f32_16x16x32_bf16(af[i], bfr[j], acc[i][j], 0, 0, 0);
        __syncthreads();
    }
    int colf = lane & 15, rowq = lane >> 4;
    #pragma unroll
    for (int j = 0; j < 2; ++j) {
        int col = n0 + (wn*2+j)*16 + colf;
        float bv = bias ? bias[col] : 0.f;
        #pragma unroll
        for (int i = 0; i < 4; ++i) {
            #pragma unroll
            for (int reg = 0; reg < 4; ++reg) {
                int row = m0 + (wm*4+i)*16 + rowq*4 + reg;
                float v = acc[i][j][reg] + bv;
                if (obf) ((unsigned short*)Cp)[(size_t)row*ldc + col] = f2bf(v);
                else     ((float*)Cp)[(size_t)row*ldc + col] = v;
            }
        }
    }
}

// ---------------------------------------------------------------------------
// out_k: grid (128,4). rows i0..i0+8 of out[b][i][j] = w2.relu(hx_i+hy_j)
// ---------------------------------------------------------------------------
__global__ __launch_bounds__(256) void out_k(
    const float* __restrict__ hxy, const float* __restrict__ w2,
    float* __restrict__ out_g)
{
    __shared__ float s_hx[9*129], s_hy[NN*129], s_w2[NHID];
    int b = blockIdx.x, i0 = blockIdx.y * 9, tid = threadIdx.x;
    for (int i = tid; i < 9*NHID; i += 256) {
        int n = i >> 7, h = i & 127;
        s_hx[n*129+h] = hxy[(size_t)(b*NN+i0+n)*256 + h];
    }
    for (int i = tid; i < NN*NHID; i += 256) {
        int n = i >> 7, h = i & 127;
        s_hy[n*129+h] = hxy[(size_t)(b*NN+n)*256 + 128 + h];
    }
    if (tid < NHID) s_w2[tid] = w2[tid];
    __syncthreads();
    for (int idx = tid; idx < 9*NN; idx += 256) {
        int il = idx / NN, j = idx - il*NN;
        const float* px = &s_hx[il*129];
        const float* py = &s_hy[j*129];
        float s = 0.f;
        #pragma unroll 8
        for (int h = 0; h < NHID; ++h) s += s_w2[h] * fmaxf(px[h] + py[h], 0.f);
        out_g[(size_t)b*NN*NN + (i0+il)*NN + j] = s;
    }
}

// ---------------------------------------------------------------------------
// iter_k: grid 128. C = out - out^T, 3 assignment iters, final A row-softmax
// pre-scaled by sigmoid(att) -> A_g.
// ---------------------------------------------------------------------------
__global__ __launch_bounds__(256) void iter_k(
    const float* __restrict__ out_g, const float* __restrict__ att,
    const float* __restrict__ lr, float* __restrict__ A_g)
{
    __shared__ __align__(16) float s_out[NN*S40], s_C[NN*S40], s_logits[NN*S40], s_P[NN*S40];
    __shared__ float s_sg[NN];
    int b = blockIdx.x, tid = threadIdx.x;
    for (int idx = tid; idx < NN*NN; idx += 256) {
        int i = idx / NN, j = idx - i*NN;
        s_out[i*S40+j] = out_g[(size_t)b*NN*NN + idx];
        s_logits[i*S40+j] = 0.f;
    }
    if (tid < NN) s_sg[tid] = sigf(att[b*NN + tid]);
    float lr_abs = fabsf(lr[0]);
    __syncthreads();
    for (int idx = tid; idx < NN*NN; idx += 256) {
        int i = idx / NN, j = idx - i*NN;
        s_C[i*S40+j] = s_out[i*S40+j] - s_out[j*S40+i];
    }
    __syncthreads();
    for (int it = 0; it < 3; ++it) {
        if (tid < NN) {
            int i = tid;
            float mx = -1e30f;
            for (int l = 0; l < NN; ++l) mx = fmaxf(mx, s_logits[i*S40+l]);
            float sum = 0.f;
            for (int l = 0; l < NN; ++l) { float e = expf(s_logits[i*S40+l]-mx); s_P[i*S40+l] = e; sum += e; }
            float inv = 1.f/sum;
            for (int l = 0; l < NN; ++l) s_P[i*S40+l] *= inv;
        }
        __syncthreads();
        if (tid < NN) {
            int l = tid;
            float S = 0.f;
            for (int i = 0; i < NN; ++i) S += s_P[i*S40+l];
            float cum = 0.f;
            for (int i = 0; i < NN; ++i) {
                float p = s_P[i*S40+l];
                cum += p;
                s_P[i*S40+l] = S - 2.f*cum + p;
            }
        }
        __syncthreads();
        for (int idx = tid; idx < NN*NN; idx += 256) {
            int i = idx / NN, j = idx - i*NN;
            const f32x4* Pp = (const f32x4*)&s_P[i*S40];
            const f32x4* Cc = (const f32x4*)&s_C[j*S40];
            float g = 0.f;
            #pragma unroll
            for (int q = 0; q < 9; ++q) {
                f32x4 a = Pp[q], bb = Cc[q];
                g += a[0]*bb[0] + a[1]*bb[1] + a[2]*bb[2] + a[3]*bb[3];
            }
            s_logits[i*S40+j] -= lr_abs * g;
        }
        __syncthreads();
    }
    if (tid < NN) {
        int i = tid;
        float mx = -1e30f;
        for (int l = 0; l < NN; ++l) mx = fmaxf(mx, s_logits[i*S40+l]);
        float sum = 0.f;
        for (int l = 0; l < NN; ++l) { float e = expf(s_logits[i*S40+l]-mx); s_P[i*S40+l] = e; sum += e; }
        float inv = 1.f/sum;
        for (int l = 0; l < NN; ++l)
            A_g[(size_t)b*NN*NN + i*NN + l] = s_P[i*S40+l] * inv * s_sg[l];
    }
}

// ---------------------------------------------------------------------------
// xseq_k: grid (128,2). xseq[i][b][c] = sum_l A[b][i][l]*feats[b][l][c], bf16.
// ---------------------------------------------------------------------------
__global__ __launch_bounds__(256) void xseq_k(
    const float* __restrict__ feats, const float* __restrict__ A_g,
    unsigned short* __restrict__ xseq)
{
    __shared__ float s_P[NN*S37];
    int b = blockIdx.x, half = blockIdx.y, tid = threadIdx.x;
    for (int idx = tid; idx < NN*NN; idx += 256) {
        int i = idx / NN, l = idx - i*NN;
        s_P[i*S37+l] = A_g[(size_t)b*NN*NN + idx];
    }
    __syncthreads();
    const float* fb = feats + (size_t)b*NN*NMID;
    int ncols = (half == 0 && tid < 32) ? 2 : 1;
    #pragma unroll
    for (int rep = 0; rep < 2; ++rep) {
        if (rep >= ncols) break;
        int c = (rep == 0) ? half*256 + tid : 512 + tid;
        float colv[NN];
        #pragma unroll
        for (int l = 0; l < NN; ++l) colv[l] = (c < NMID) ? fb[l*NMID + c] : 0.f;
        #pragma unroll 4
        for (int i = 0; i < NN; ++i) {
            float s = 0.f;
            #pragma unroll
            for (int l = 0; l < NN; ++l) s += s_P[i*S37+l] * colv[l];
            xseq[((size_t)i*NB + b)*KP + c] = f2bf(s);
        }
    }
}

// ---------------------------------------------------------------------------
// lstm_persist: ALL 36 LSTM steps in ONE dispatch — pipelined chunk waits
// + double-buffered h loads. UNCHANGED from r9 (374-378us across r7/r9;
// step period ~10.4us = one cross-XCD publish->detect handoff; insensitive
// to barrier primitive, poll rate, and load buffering — structural floor
// for this decomposition).
// ---------------------------------------------------------------------------
__global__ __launch_bounds__(256, 2) void lstm_persist(
    const unsigned short* __restrict__ whh, const unsigned short* __restrict__ xw,
    unsigned short* __restrict__ hseq, float* __restrict__ dout,
    unsigned int* __restrict__ bar)
{
    __shared__ __align__(16) char Bls[65536];    // [kc 0..127][n' 0..31][16B]
    __shared__ __align__(16) float gates[32][36];
    int tid = threadIdx.x, lane = tid & 63, wave = tid >> 6;
    int bt = blockIdx.x >> 7, ct = blockIdx.x & 127;
    int m0 = bt * 32, n0 = ct * 32;
    // stage whh slice ONCE: 16 passes; each wave reads 1KB contiguous/row
    #pragma unroll
    for (int r = 0; r < 16; ++r) {
        int idx = r*256 + tid;
        int n = idx >> 7, kc = idx & 127;
        uint4 v = *(const uint4*)(whh + (size_t)(n0+n)*NOUT + kc*8);
        *(uint4*)(Bls + kc*512 + (((n&16) | ((n^kc)&15))<<4)) = v;
    }
    int wm = wave >> 1, wn = wave & 1;
    int q = lane >> 4, ml = lane & 15;
    int nl = wn*16 + ml;
    int ul = tid & 7, bl = tid >> 3;
    int b = m0 + bl, u = ct*8 + ul;
    unsigned int* flags = bar + bt*128;          // this group's 128 flags
    int fidx = lane & 31;                        // lane's flag slot in a chunk
    float cc = 0.f;
    __syncthreads();
    for (int t = 0; t < NN; ++t) {
        // xw contribution (includes b_ih+b_hh from the xw GEMM epilogue)
        uint2 xw2 = *(const uint2*)(xw + ((size_t)t*NB + b)*4*NOUT + n0 + ul*4);
        float g0 = bf2f((unsigned short)(xw2.x & 0xffffu));
        float g1 = bf2f((unsigned short)(xw2.x >> 16));
        float g2 = bf2f((unsigned short)(xw2.y & 0xffffu));
        float g3 = bf2f((unsigned short)(xw2.y >> 16));
        if (t > 0) {
            const unsigned short* hrow = hseq + (size_t)(t-1)*NB*NOUT
                                       + (size_t)(m0 + wm*16 + ml)*NOUT + q*8;
            f32x4 acc = (f32x4){0.f,0.f,0.f,0.f};
            unsigned tgt = (unsigned)t;
            bf16x8 abuf[2][8];
            // chunk 0: wait + issue loads
            for (;;) {
                unsigned f = __hip_atomic_load(flags + fidx,
                                  __ATOMIC_RELAXED, __HIP_MEMORY_SCOPE_AGENT);
                if (__all(f >= tgt)) break;
                __builtin_amdgcn_s_sleep(1);
            }
            asm volatile("" ::: "memory");   // no load hoisting above spin
            #pragma unroll
            for (int i = 0; i < 8; ++i)
                abuf[0][i] = *(const bf16x8*)(hrow + i*32);
            #pragma unroll
            for (int c = 0; c < 4; ++c) {
                if (c < 3) {
                    // wait for chunk c+1's producers; chunk c's loads fly
                    for (;;) {
                        unsigned f = __hip_atomic_load(flags + 32*(c+1) + fidx,
                                          __ATOMIC_RELAXED, __HIP_MEMORY_SCOPE_AGENT);
                        if (__all(f >= tgt)) break;
                        __builtin_amdgcn_s_sleep(1);
                    }
                    asm volatile("" ::: "memory");
                    #pragma unroll
                    for (int i = 0; i < 8; ++i)
                        abuf[(c+1)&1][i] = *(const bf16x8*)(hrow + ((c+1)*8 + i)*32);
                }
                // MFMA chunk c (loads(c+1) in flight behind these)
                #pragma unroll
                for (int it2 = 0; it2 < 8; ++it2) {
                    int kc = (c*8 + it2)*4 + q;
                    bf16x8 bb = *(const bf16x8*)(Bls + kc*512 + (((nl&16) | ((nl^kc)&15))<<4));
                    acc = __builtin_amdgcn_mfma_f32_16x16x32_bf16(abuf[c&1][it2], bb, acc, 0, 0, 0);
                }
            }
            #pragma unroll
            for (int reg = 0; reg < 4; ++reg)
                gates[wm*16 + q*4 + reg][wn*16 + ml] = acc[reg];
            __syncthreads();
            float4 gl = *(const float4*)&gates[bl][ul*4];
            g0 += gl.x; g1 += gl.y; g2 += gl.z; g3 += gl.w;
        }
        float ig = sigf(g0), fg = sigf(g1), gg = tanhf(g2), og = sigf(g3);
        cc = fg*cc + ig*gg;
        if (t == NN-1) {
            dout[(size_t)b*NOUT + u] = cc;
        } else {
            // lane-pair pack -> native 32-bit sc1 write-through store
            unsigned short hb = f2bf(og*tanhf(cc));
            unsigned partner = (unsigned)__shfl_down((int)(unsigned)hb, 1);
            if ((ul & 1) == 0) {
                unsigned word = (unsigned)hb | (partner << 16);
                unsigned* dst = (unsigned*)(hseq + (size_t)t*NB*NOUT
                                            + (size_t)b*NOUT + u);
                __hip_atomic_store(dst, word, __ATOMIC_RELAXED,
                                   __HIP_MEMORY_SCOPE_AGENT);
            }
            asm volatile("s_waitcnt vmcnt(0)" ::: "memory"); // h at coherent point
            __syncthreads();            // all threads drained + gates reads done
            if (tid == 0)
                __hip_atomic_store(flags + ct, (unsigned)(t + 1),
                                   __ATOMIC_RELAXED, __HIP_MEMORY_SCOPE_AGENT);
            // NO wait here — next step's chunk waits pipeline the latency
        }
    }
}

// ---------------------------------------------------------------------------
extern "C" void kernel_launch(void* const* d_in, const int* in_sizes, int n_in,
                              void* d_out, int out_size, void* d_ws, size_t ws_size,
                              hipStream_t stream) {
    (void)in_sizes; (void)n_in; (void)out_size; (void)ws_size;
    const float* boxes     = (const float*)d_in[0];
    const float* attention = (const float*)d_in[1];
    const float* features  = (const float*)d_in[2];
    const float* conv_w    = (const float*)d_in[3];
    const float* conv_b    = (const float*)d_in[4];
    const float* skew_wx   = (const float*)d_in[5];
    const float* skew_wy   = (const float*)d_in[6];
    const float* skew_b1   = (const float*)d_in[7];
    const float* skew_w2   = (const float*)d_in[8];
    // d_in[9] = skew_b2: cancels in C = out - out^T
    const float* w_ih      = (const float*)d_in[10];
    const float* w_hh      = (const float*)d_in[11];
    const float* b_ih      = (const float*)d_in[12];
    const float* b_hh      = (const float*)d_in[13];
    const float* lr        = (const float*)d_in[14];

    // workspace layout (bytes, 256-aligned). part (conv split-K partials)
    // and xw_bf share region 0 — partials dead before the xw GEMM writes.
    // hseq (36-step h buffers, 9.4MB) aliases features_bf's region —
    // features_bf is dead after the conv GEMM, hseq used only in the LSTM;
    // inter-dispatch cache maintenance clears stale lines at kernel start.
    char* ws = (char*)d_ws;
    float*          part     = (float*)(ws);                      // 4x4608x512 f32  37,748,736
    unsigned short* xw_bf    = (unsigned short*)(ws);             // 4608x4096 bf16 (same region)
    unsigned short* features_bf = (unsigned short*)(ws + 37748736); // 18,874,368
    unsigned short* hseq     = (unsigned short*)(ws + 37748736);  //  9,437,184 (aliases features_bf)
    unsigned short* convw_bf = (unsigned short*)(ws + 56623104);  //  2,097,152
    float*          feats    = (float*)(ws + 58720256);           //  9,529,344
    float*          hxy      = (float*)(ws + 68249600);           //  4,718,592
    unsigned short* feats_bf = (unsigned short*)(ws + 72968192);  //  5,013,504
    unsigned short* xseq_bf  = (unsigned short*)(ws + 77981696);  //  5,013,504
    unsigned short* wih_il   = (unsigned short*)(ws + 82995200);  //  4,456,448
    unsigned short* whh_il   = (unsigned short*)(ws + 87451648);  //  8,388,608
    unsigned short* wxy_bf   = (unsigned short*)(ws + 95840256);  //    278,528
    float*          comb_b   = (float*)(ws + 96118784);           //     16,384
    float*          hxy_b    = (float*)(ws + 96135168);           //      1,024
    float*          out_g    = (float*)(ws + 96660480);           //    663,552
    float*          A_g      = (float*)(ws + 97324032);           //    663,552
    unsigned int*   bar      = (unsigned int*)(ws + 97987584);    //      2,048 (4x128 flags)

    prep_all<<<2048, 256, 0, stream>>>(boxes, attention, features, conv_w,
                                       skew_wx, skew_wy, skew_b1, w_ih, w_hh,
                                       b_ih, b_hh, features_bf, convw_bf,
                                       wxy_bf, hxy_b, wih_il, whh_il, comb_b,
                                       bar, feats);
    // conv split-K: 128x128 tiles, K-slice 512, grid (4,36,4) = 576 blocks
    gemm128<<<dim3(4, 36, 4), 256, 0, stream>>>(features_bf, convw_bf, nullptr,
                                                (void*)part, 512, NFEAT, NFEAT, 512, 0,
                                                (long long)ROWS*512);
    conv_reduce<<<2048, 256, 0, stream>>>(part, conv_b, feats, feats_bf);
    // hxy = feats . [wx;wy]^T + [b1;0]
    gemm_mfma<<<dim3(4, 36), 256, 0, stream>>>(feats_bf, wxy_bf, hxy_b,
                                               (void*)hxy, KP, KP, KP, 256, 0);
    // assignment pipeline
    out_k<<<dim3(NB, 4), 256, 0, stream>>>(hxy, skew_w2, out_g);
    iter_k<<<NB, 256, 0, stream>>>(out_g, attention, lr, A_g);
    xseq_k<<<dim3(NB, 2), 256, 0, stream>>>(feats, A_g, xseq_bf);
    // xw = xseq . w_ih_il^T + (b_ih+b_hh) -> bf16, 128x128 tiles, 1152 blocks
    gemm128<<<dim3(32, 36, 1), 256, 0, stream>>>(xseq_bf, wih_il, comb_b,
                                                 (void*)xw_bf, KP, KP, KP, 4*NOUT, 1, 0);
    // ALL 36 LSTM steps in one persistent dispatch (pipelined chunk waits
    // + double-buffered h loads)
    lstm_persist<<<512, 256, 0, stream>>>(whh_il, xw_bf, hseq,
                                          (float*)d_out, bar);
}

// Round 11
// 643.579 us; speedup vs baseline: 1.0343x; 1.0008x over previous
//
#include <hip/hip_runtime.h>
#include <math.h>

// Problem dims
#define NB 128
#define NN 36
#define S40 40            // padded stride, 16B-aligned rows (assign_k)
#define NFEAT 2048
#define NMID 517
#define KP 544            // padded K (multiple of 32) for MID-dim GEMMs
#define NHID 128
#define NOUT 1024
#define ROWS (NB*NN)      // 4608

typedef __bf16 bf16x8 __attribute__((ext_vector_type(8)));
typedef float  f32x4  __attribute__((ext_vector_type(4)));

__device__ __forceinline__ float sigf(float x){ return 1.f/(1.f+expf(-x)); }
__device__ __forceinline__ unsigned short f2bf(float x){
    unsigned u = __float_as_uint(x);
    return (unsigned short)((u + 0x7FFFu + ((u>>16)&1u)) >> 16);
}
__device__ __forceinline__ float bf2f(unsigned short b){
    return __uint_as_float(((unsigned)b) << 16);
}
__device__ __forceinline__ unsigned pack2(float a, float b){
    return (unsigned)f2bf(a) | ((unsigned)f2bf(b) << 16);
}
// async global->LDS, 16B/lane: LDS dest = wave-uniform base + lane*16
__device__ __forceinline__ void gload_lds16(const unsigned short* g, void* lds){
    __builtin_amdgcn_global_load_lds(
        (const __attribute__((address_space(1))) void*)g,
        (__attribute__((address_space(3))) void*)lds, 16, 0, 0);
}

// ---------------------------------------------------------------------------
// prep_all: ALL input casts/reorders/zeroing in one dispatch.
// r11: bulk casts vectorized (G13) — float4 x2 reads + packed uint4 (8xbf16)
// stores for features/conv_w/w_hh; packed stores for w_ih (517-stride source
// rows are 4B-aligned only -> scalar reads kept).
// ---------------------------------------------------------------------------
__global__ __launch_bounds__(256) void prep_all(
    const float* __restrict__ boxes, const float* __restrict__ att,
    const float* __restrict__ features, const float* __restrict__ conv_w,
    const float* __restrict__ wx, const float* __restrict__ wy,
    const float* __restrict__ b1, const float* __restrict__ w_ih,
    const float* __restrict__ w_hh, const float* __restrict__ b_ih,
    const float* __restrict__ b_hh,
    unsigned short* __restrict__ features_bf, unsigned short* __restrict__ convw_bf,
    unsigned short* __restrict__ wxy_bf, float* __restrict__ hxy_b,
    unsigned short* __restrict__ wih_il, unsigned short* __restrict__ whh_il,
    float* __restrict__ comb_b, unsigned int* __restrict__ bar,
    float* __restrict__ feats)
{
    int gtid = blockIdx.x*256 + threadIdx.x;
    int gs = gridDim.x*256;
    if (gtid < 128*64) {
        int b = gtid >> 6, t = gtid & 63;
        float mx = -1e30f;
        for (int idx = t; idx < 4*NN; idx += 64) mx = fmaxf(mx, boxes[b*4*NN + idx]);
        for (int off = 32; off > 0; off >>= 1) mx = fmaxf(mx, __shfl_down(mx, off));
        mx = __shfl(mx, 0);
        float inv = 1.f / mx;
        for (int idx = t; idx < 4*NN; idx += 64) {
            int r = idx / NN, n = idx - r*NN;
            feats[(size_t)(b*NN+n)*NMID + r] = boxes[b*4*NN + idx] * inv;
        }
        if (t < NN) feats[(size_t)(b*NN+t)*NMID + 4] = att[b*NN + t];
    }
    // features cast: 8 elems/iter, vector load + packed 16B store
    for (int i = gtid; i < ROWS*NFEAT/8; i += gs) {
        const float* s = features + (size_t)i*8;
        float4 v0 = *(const float4*)s, v1 = *(const float4*)(s+4);
        uint4 o = { pack2(v0.x,v0.y), pack2(v0.z,v0.w),
                    pack2(v1.x,v1.y), pack2(v1.z,v1.w) };
        *(uint4*)(features_bf + (size_t)i*8) = o;
    }
    for (int i = gtid; i < 512*NFEAT/8; i += gs) {
        const float* s = conv_w + (size_t)i*8;
        float4 v0 = *(const float4*)s, v1 = *(const float4*)(s+4);
        uint4 o = { pack2(v0.x,v0.y), pack2(v0.z,v0.w),
                    pack2(v1.x,v1.y), pack2(v1.z,v1.w) };
        *(uint4*)(convw_bf + (size_t)i*8) = o;
    }
    for (int i = gtid; i < 256*KP; i += gs) {
        int r = i / KP, k = i - r*KP;
        float v = 0.f;
        if (k < NMID) v = (r < NHID) ? wx[(size_t)r*NMID+k] : wy[(size_t)(r-NHID)*NMID+k];
        wxy_bf[i] = f2bf(v);
    }
    for (int i = gtid; i < 256; i += gs) hxy_b[i] = (i < NHID) ? b1[i] : 0.f;
    // w_ih interleave: rows 4096 x KP; packed 16B stores, scalar reads
    for (int i = gtid; i < 4*NOUT*(KP/8); i += gs) {
        int row = i / (KP/8), kb = i - row*(KP/8);
        int u = row >> 2, g = row & 3;
        int base = kb*8;
        const float* s = w_ih + (size_t)(g*NOUT+u)*NMID + base;
        float f[8];
        #pragma unroll
        for (int t = 0; t < 8; ++t) f[t] = (base+t < NMID) ? s[t] : 0.f;
        uint4 o = { pack2(f[0],f[1]), pack2(f[2],f[3]),
                    pack2(f[4],f[5]), pack2(f[6],f[7]) };
        *(uint4*)(wih_il + (size_t)row*KP + base) = o;
    }
    // w_hh interleave: vector loads (1024-stride rows, 16B-aligned)
    for (int i = gtid; i < 4*NOUT*NOUT/8; i += gs) {
        int row = i >> 7, kb = i & 127;
        int u = row >> 2, g = row & 3;
        const float* s = w_hh + ((size_t)(g*NOUT+u) << 10) + kb*8;
        float4 v0 = *(const float4*)s, v1 = *(const float4*)(s+4);
        uint4 o = { pack2(v0.x,v0.y), pack2(v0.z,v0.w),
                    pack2(v1.x,v1.y), pack2(v1.z,v1.w) };
        *(uint4*)(whh_il + ((size_t)row << 10) + kb*8) = o;
    }
    for (int i = gtid; i < 4*NOUT; i += gs) {
        int u = i >> 2, g = i & 3;
        comb_b[i] = b_ih[g*NOUT+u] + b_hh[g*NOUT+u];
    }
    // persistent-LSTM producer flags: 4 bt-groups x 128 blocks, monotonic epoch
    for (int i = gtid; i < 512; i += gs) bar[i] = 0u;
}

// ---------------------------------------------------------------------------
// gemm128: C[m,n] = sum_k A[m,k]*B[n,k] (+ bias). Block tile 128x128,
// 4 waves = 2x2, wave tile 64x64. Staging via global_load_lds width=16
// with inverse-swizzled per-lane source (LDS contents byte-identical to the
// XOR-swizzled layout; read path untouched). UNCHANGED from r10.
// ---------------------------------------------------------------------------
__global__ __launch_bounds__(256) void gemm128(
    const unsigned short* __restrict__ A, const unsigned short* __restrict__ B,
    const float* __restrict__ bias, void* __restrict__ Cp,
    int Ksl, int lda, int ldb, int ldc, int obf, long long pstride)
{
    __shared__ __align__(16) char As[16384];
    __shared__ __align__(16) char Bs[16384];
    int m0 = blockIdx.y * 128, n0 = blockIdx.x * 128;
    int kbeg = blockIdx.z * Ksl;
    int tid = threadIdx.x;
    int lane = tid & 63, wave = tid >> 6;
    int wm = wave >> 1, wn = wave & 1;
    int sw = ((lane>>4)<<8) + (((lane&15) ^ ((lane>>4)<<2))<<4);
    f32x4 acc[4][4];
    #pragma unroll
    for (int i = 0; i < 4; ++i)
        #pragma unroll
        for (int j = 0; j < 4; ++j) acc[i][j] = (f32x4){0.f,0.f,0.f,0.f};

    int gq = lane >> 4, sl = lane & 15;
    int rloc = sl ^ (gq << 2);
    int g0r = wave*2*16 + rloc, g1r = g0r + 16;
    const unsigned short* a0 = A + (size_t)(m0 + g0r)*lda + kbeg + gq*8;
    const unsigned short* a1 = A + (size_t)(m0 + g1r)*lda + kbeg + gq*8;
    const unsigned short* b0 = B + (size_t)(n0 + g0r)*ldb + kbeg + gq*8;
    const unsigned short* b1 = B + (size_t)(n0 + g1r)*ldb + kbeg + gq*8;
    char* asd0 = As + ((wave*2)<<10); char* asd1 = asd0 + 1024;
    char* bsd0 = Bs + ((wave*2)<<10); char* bsd1 = bsd0 + 1024;

    for (int k0 = 0; k0 < Ksl; k0 += 32) {
        gload_lds16(a0 + k0, asd0);
        gload_lds16(a1 + k0, asd1);
        gload_lds16(b0 + k0, bsd0);
        gload_lds16(b1 + k0, bsd1);
        __syncthreads();
        bf16x8 af[4], bfr[4];
        #pragma unroll
        for (int i = 0; i < 4; ++i) af[i]  = *(bf16x8*)(As + ((wm*4+i)<<10) + sw);
        #pragma unroll
        for (int j = 0; j < 4; ++j) bfr[j] = *(bf16x8*)(Bs + ((wn*4+j)<<10) + sw);
        #pragma unroll
        for (int i = 0; i < 4; ++i)
            #pragma unroll
            for (int j = 0; j < 4; ++j)
                acc[i][j] = __builtin_amdgcn_mfma_f32_16x16x32_bf16(af[i], bfr[j], acc[i][j], 0, 0, 0);
        __syncthreads();
    }
    int colf = lane & 15, rowq = lane >> 4;
    #pragma unroll
    for (int j = 0; j < 4; ++j) {
        int col = n0 + (wn*4+j)*16 + colf;
        float bv = bias ? bias[col] : 0.f;
        #pragma unroll
        for (int i = 0; i < 4; ++i) {
            #pragma unroll
            for (int reg = 0; reg < 4; ++reg) {
                int row = m0 + (wm*4+i)*16 + rowq*4 + reg;
                float v = acc[i][j][reg] + bv;
                if (obf) ((unsigned short*)Cp)[(size_t)row*ldc + col] = f2bf(v);
                else ((float*)Cp + (size_t)blockIdx.z*pstride)[(size_t)row*ldc + col] = v;
            }
        }
    }
}

// ---------------------------------------------------------------------------
// conv_reduce: feats[:,5:] = sum_z part[z] + conv_b; emits full padded bf16
// feats (cols 0..4 from feats, 5..516 computed, 517..543 zero).
// ---------------------------------------------------------------------------
__global__ __launch_bounds__(256) void conv_reduce(
    const float* __restrict__ part, const float* __restrict__ bias,
    float* __restrict__ feats, unsigned short* __restrict__ feats_bf)
{
    int gtid = blockIdx.x*256 + threadIdx.x;
    int gs = gridDim.x*256;
    const size_t PS = (size_t)ROWS * 512;
    for (int i = gtid; i < ROWS*512; i += gs) {
        int r = i >> 9, cc = i & 511;
        float s = part[i] + part[PS+i] + part[2*PS+i] + part[3*PS+i] + bias[cc];
        feats[(size_t)r*NMID + 5 + cc] = s;
        feats_bf[(size_t)r*KP + 5 + cc] = f2bf(s);
    }
    for (int i = gtid; i < ROWS*5; i += gs) {
        int r = i / 5, cc = i - r*5;
        feats_bf[(size_t)r*KP + cc] = f2bf(feats[(size_t)r*NMID + cc]);
    }
    for (int i = gtid; i < ROWS*27; i += gs) {
        int r = i / 27, cc = i - r*27;
        feats_bf[(size_t)r*KP + 517 + cc] = 0;
    }
}

// ---------------------------------------------------------------------------
// bf16 MFMA GEMM (hxy only): tile 128x64, wave tile 64x32.
// global_load_lds staging (linear LDS). UNCHANGED from r10.
// ---------------------------------------------------------------------------
__global__ __launch_bounds__(256) void gemm_mfma(
    const unsigned short* __restrict__ A, const unsigned short* __restrict__ B,
    const float* __restrict__ bias, void* __restrict__ Cp,
    int K, int lda, int ldb, int ldc, int obf)
{
    __shared__ __align__(16) char As[8192];
    __shared__ __align__(16) char Bs[4096];
    int m0 = blockIdx.y * 128, n0 = blockIdx.x * 64;
    int tid = threadIdx.x;
    int lane = tid & 63, wave = tid >> 6;
    int wm = wave >> 1, wn = wave & 1;
    f32x4 acc[4][2];
    #pragma unroll
    for (int i = 0; i < 4; ++i)
        #pragma unroll
        for (int j = 0; j < 2; ++j) acc[i][j] = (f32x4){0.f,0.f,0.f,0.f};

    int gq = lane >> 4, sl = lane & 15;
    int g0r = wave*2*16 + sl, g1r = g0r + 16;
    const unsigned short* a0 = A + (size_t)(m0 + g0r)*lda + gq*8;
    const unsigned short* a1 = A + (size_t)(m0 + g1r)*lda + gq*8;
    const unsigned short* bb0 = B + (size_t)(n0 + wave*16 + sl)*ldb + gq*8;
    char* asd0 = As + ((wave*2)<<10); char* asd1 = asd0 + 1024;
    char* bsd0 = Bs + (wave<<10);

    for (int k0 = 0; k0 < K; k0 += 32) {
        gload_lds16(a0 + k0, asd0);
        gload_lds16(a1 + k0, asd1);
        gload_lds16(bb0 + k0, bsd0);
        __syncthreads();
        bf16x8 af[4], bfr[2];
        #pragma unroll
        for (int i = 0; i < 4; ++i) af[i]  = *(bf16x8*)(As + ((wm*4+i)<<10) + (lane<<4));
        #pragma unroll
        for (int j = 0; j < 2; ++j) bfr[j] = *(bf16x8*)(Bs + ((wn*2+j)<<10) + (lane<<4));
        #pragma unroll
        for (int i = 0; i < 4; ++i)
            #pragma unroll
            for (int j = 0; j < 2; ++j)
                acc[i][j] = __builtin_amdgcn_mfma_f32_16x16x32_bf16(af[i], bfr[j], acc[i][j], 0, 0, 0);
        __syncthreads();
    }
    int colf = lane & 15, rowq = lane >> 4;
    #pragma unroll
    for (int j = 0; j < 2; ++j) {
        int col = n0 + (wn*2+j)*16 + colf;
        float bv = bias ? bias[col] : 0.f;
        #pragma unroll
        for (int i = 0; i < 4; ++i) {
            #pragma unroll
            for (int reg = 0; reg < 4; ++reg) {
                int row = m0 + (wm*4+i)*16 + rowq*4 + reg;
                float v = acc[i][j][reg] + bv;
                if (obf) ((unsigned short*)Cp)[(size_t)row*ldc + col] = f2bf(v);
                else     ((float*)Cp)[(size_t)row*ldc + col] = v;
            }
        }
    }
}

// ---------------------------------------------------------------------------
// assign_k: FUSED out_k + iter_k + xseq_k. Grid 128, one block per batch b.
// Phase 1: out[i][j] = w2 . relu(hx_i + hy_j)         (s_logits as temp)
// Phase 2: C = out - out^T
// Phase 3: 3 assignment iterations (verbatim iter_k)
// Phase 4: final row-softmax x sigmoid(att) -> s_P
// Phase 5: xseq[i][b][c] = sum_l A[i][l] * feats[b][l][c], bf16 out
// Kills 2 launches + out_g/A_g global round-trips.
// ---------------------------------------------------------------------------
__global__ __launch_bounds__(256) void assign_k(
    const float* __restrict__ hxy, const float* __restrict__ w2,
    const float* __restrict__ att, const float* __restrict__ lr,
    const float* __restrict__ feats, unsigned short* __restrict__ xseq)
{
    __shared__ float s_hx[NN*129], s_hy[NN*129], s_w2[NHID], s_sg[NN];
    __shared__ __align__(16) float s_C[NN*S40], s_logits[NN*S40], s_P[NN*S40];
    int b = blockIdx.x, tid = threadIdx.x;
    for (int i = tid; i < NN*NHID; i += 256) {
        int n = i >> 7, h = i & 127;
        s_hx[n*129+h] = hxy[(size_t)(b*NN+n)*256 + h];
        s_hy[n*129+h] = hxy[(size_t)(b*NN+n)*256 + 128 + h];
    }
    if (tid < NHID) s_w2[tid] = w2[tid];
    if (tid < NN) s_sg[tid] = sigf(att[b*NN + tid]);
    float lr_abs = fabsf(lr[0]);
    __syncthreads();
    // phase 1: out -> s_logits (temp)
    for (int idx = tid; idx < NN*NN; idx += 256) {
        int i = idx / NN, j = idx - i*NN;
        const float* px = &s_hx[i*129];
        const float* py = &s_hy[j*129];
        float s = 0.f;
        #pragma unroll 8
        for (int h = 0; h < NHID; ++h) s += s_w2[h] * fmaxf(px[h] + py[h], 0.f);
        s_logits[i*S40+j] = s;
    }
    __syncthreads();
    // phase 2: C = out - out^T, then zero logits
    for (int idx = tid; idx < NN*NN; idx += 256) {
        int i = idx / NN, j = idx - i*NN;
        s_C[i*S40+j] = s_logits[i*S40+j] - s_logits[j*S40+i];
    }
    __syncthreads();
    for (int idx = tid; idx < NN*NN; idx += 256) {
        int i = idx / NN, j = idx - i*NN;
        s_logits[i*S40+j] = 0.f;
    }
    __syncthreads();
    // phase 3: 3 assignment iterations
    for (int it = 0; it < 3; ++it) {
        if (tid < NN) {
            int i = tid;
            float mx = -1e30f;
            for (int l = 0; l < NN; ++l) mx = fmaxf(mx, s_logits[i*S40+l]);
            float sum = 0.f;
            for (int l = 0; l < NN; ++l) { float e = expf(s_logits[i*S40+l]-mx); s_P[i*S40+l] = e; sum += e; }
            float inv = 1.f/sum;
            for (int l = 0; l < NN; ++l) s_P[i*S40+l] *= inv;
        }
        __syncthreads();
        if (tid < NN) {
            int l = tid;
            float S = 0.f;
            for (int i = 0; i < NN; ++i) S += s_P[i*S40+l];
            float cum = 0.f;
            for (int i = 0; i < NN; ++i) {
                float p = s_P[i*S40+l];
                cum += p;
                s_P[i*S40+l] = S - 2.f*cum + p;
            }
        }
        __syncthreads();
        for (int idx = tid; idx < NN*NN; idx += 256) {
            int i = idx / NN, j = idx - i*NN;
            const f32x4* Pp = (const f32x4*)&s_P[i*S40];
            const f32x4* Cc = (const f32x4*)&s_C[j*S40];
            float g = 0.f;
            #pragma unroll
            for (int q = 0; q < 9; ++q) {
                f32x4 a = Pp[q], bb = Cc[q];
                g += a[0]*bb[0] + a[1]*bb[1] + a[2]*bb[2] + a[3]*bb[3];
            }
            s_logits[i*S40+j] -= lr_abs * g;
        }
        __syncthreads();
    }
    // phase 4: final softmax x sg -> s_P
    if (tid < NN) {
        int i = tid;
        float mx = -1e30f;
        for (int l = 0; l < NN; ++l) mx = fmaxf(mx, s_logits[i*S40+l]);
        float sum = 0.f;
        for (int l = 0; l < NN; ++l) { float e = expf(s_logits[i*S40+l]-mx); s_P[i*S40+l] = e; sum += e; }
        float inv = 1.f/sum;
        for (int l = 0; l < NN; ++l) s_P[i*S40+l] *= inv * s_sg[l];
    }
    __syncthreads();
    // phase 5: xseq
    const float* fb = feats + (size_t)b*NN*NMID;
    #pragma unroll
    for (int rep = 0; rep < 3; ++rep) {
        int c = rep*256 + tid;
        if (c < KP) {
            float colv[NN];
            #pragma unroll
            for (int l = 0; l < NN; ++l) colv[l] = (c < NMID) ? fb[l*NMID + c] : 0.f;
            #pragma unroll 4
            for (int i = 0; i < NN; ++i) {
                float s = 0.f;
                #pragma unroll
                for (int l = 0; l < NN; ++l) s += s_P[i*S40+l] * colv[l];
                xseq[((size_t)i*NB + b)*KP + c] = f2bf(s);
            }
        }
    }
}

// ---------------------------------------------------------------------------
// lstm_persist: ALL 36 LSTM steps in ONE dispatch — pipelined chunk waits
// + double-buffered h loads. UNCHANGED (367-378us across r7-r10; step period
// ~10.4us = one cross-XCD publish->detect handoff; insensitive to barrier
// primitive, poll rate, and load buffering — structural floor).
// ---------------------------------------------------------------------------
__global__ __launch_bounds__(256, 2) void lstm_persist(
    const unsigned short* __restrict__ whh, const unsigned short* __restrict__ xw,
    unsigned short* __restrict__ hseq, float* __restrict__ dout,
    unsigned int* __restrict__ bar)
{
    __shared__ __align__(16) char Bls[65536];    // [kc 0..127][n' 0..31][16B]
    __shared__ __align__(16) float gates[32][36];
    int tid = threadIdx.x, lane = tid & 63, wave = tid >> 6;
    int bt = blockIdx.x >> 7, ct = blockIdx.x & 127;
    int m0 = bt * 32, n0 = ct * 32;
    #pragma unroll
    for (int r = 0; r < 16; ++r) {
        int idx = r*256 + tid;
        int n = idx >> 7, kc = idx & 127;
        uint4 v = *(const uint4*)(whh + (size_t)(n0+n)*NOUT + kc*8);
        *(uint4*)(Bls + kc*512 + (((n&16) | ((n^kc)&15))<<4)) = v;
    }
    int wm = wave >> 1, wn = wave & 1;
    int q = lane >> 4, ml = lane & 15;
    int nl = wn*16 + ml;
    int ul = tid & 7, bl = tid >> 3;
    int b = m0 + bl, u = ct*8 + ul;
    unsigned int* flags = bar + bt*128;
    int fidx = lane & 31;
    float cc = 0.f;
    __syncthreads();
    for (int t = 0; t < NN; ++t) {
        uint2 xw2 = *(const uint2*)(xw + ((size_t)t*NB + b)*4*NOUT + n0 + ul*4);
        float g0 = bf2f((unsigned short)(xw2.x & 0xffffu));
        float g1 = bf2f((unsigned short)(xw2.x >> 16));
        float g2 = bf2f((unsigned short)(xw2.y & 0xffffu));
        float g3 = bf2f((unsigned short)(xw2.y >> 16));
        if (t > 0) {
            const unsigned short* hrow = hseq + (size_t)(t-1)*NB*NOUT
                                       + (size_t)(m0 + wm*16 + ml)*NOUT + q*8;
            f32x4 acc = (f32x4){0.f,0.f,0.f,0.f};
            unsigned tgt = (unsigned)t;
            bf16x8 abuf[2][8];
            for (;;) {
                unsigned f = __hip_atomic_load(flags + fidx,
                                  __ATOMIC_RELAXED, __HIP_MEMORY_SCOPE_AGENT);
                if (__all(f >= tgt)) break;
                __builtin_amdgcn_s_sleep(1);
            }
            asm volatile("" ::: "memory");
            #pragma unroll
            for (int i = 0; i < 8; ++i)
                abuf[0][i] = *(const bf16x8*)(hrow + i*32);
            #pragma unroll
            for (int c = 0; c < 4; ++c) {
                if (c < 3) {
                    for (;;) {
                        unsigned f = __hip_atomic_load(flags + 32*(c+1) + fidx,
                                          __ATOMIC_RELAXED, __HIP_MEMORY_SCOPE_AGENT);
                        if (__all(f >= tgt)) break;
                        __builtin_amdgcn_s_sleep(1);
                    }
                    asm volatile("" ::: "memory");
                    #pragma unroll
                    for (int i = 0; i < 8; ++i)
                        abuf[(c+1)&1][i] = *(const bf16x8*)(hrow + ((c+1)*8 + i)*32);
                }
                #pragma unroll
                for (int it2 = 0; it2 < 8; ++it2) {
                    int kc = (c*8 + it2)*4 + q;
                    bf16x8 bb = *(const bf16x8*)(Bls + kc*512 + (((nl&16) | ((nl^kc)&15))<<4));
                    acc = __builtin_amdgcn_mfma_f32_16x16x32_bf16(abuf[c&1][it2], bb, acc, 0, 0, 0);
                }
            }
            #pragma unroll
            for (int reg = 0; reg < 4; ++reg)
                gates[wm*16 + q*4 + reg][wn*16 + ml] = acc[reg];
            __syncthreads();
            float4 gl = *(const float4*)&gates[bl][ul*4];
            g0 += gl.x; g1 += gl.y; g2 += gl.z; g3 += gl.w;
        }
        float ig = sigf(g0), fg = sigf(g1), gg = tanhf(g2), og = sigf(g3);
        cc = fg*cc + ig*gg;
        if (t == NN-1) {
            dout[(size_t)b*NOUT + u] = cc;
        } else {
            unsigned short hb = f2bf(og*tanhf(cc));
            unsigned partner = (unsigned)__shfl_down((int)(unsigned)hb, 1);
            if ((ul & 1) == 0) {
                unsigned word = (unsigned)hb | (partner << 16);
                unsigned* dst = (unsigned*)(hseq + (size_t)t*NB*NOUT
                                            + (size_t)b*NOUT + u);
                __hip_atomic_store(dst, word, __ATOMIC_RELAXED,
                                   __HIP_MEMORY_SCOPE_AGENT);
            }
            asm volatile("s_waitcnt vmcnt(0)" ::: "memory");
            __syncthreads();
            if (tid == 0)
                __hip_atomic_store(flags + ct, (unsigned)(t + 1),
                                   __ATOMIC_RELAXED, __HIP_MEMORY_SCOPE_AGENT);
        }
    }
}

// ---------------------------------------------------------------------------
extern "C" void kernel_launch(void* const* d_in, const int* in_sizes, int n_in,
                              void* d_out, int out_size, void* d_ws, size_t ws_size,
                              hipStream_t stream) {
    (void)in_sizes; (void)n_in; (void)out_size; (void)ws_size;
    const float* boxes     = (const float*)d_in[0];
    const float* attention = (const float*)d_in[1];
    const float* features  = (const float*)d_in[2];
    const float* conv_w    = (const float*)d_in[3];
    const float* conv_b    = (const float*)d_in[4];
    const float* skew_wx   = (const float*)d_in[5];
    const float* skew_wy   = (const float*)d_in[6];
    const float* skew_b1   = (const float*)d_in[7];
    const float* skew_w2   = (const float*)d_in[8];
    // d_in[9] = skew_b2: cancels in C = out - out^T
    const float* w_ih      = (const float*)d_in[10];
    const float* w_hh      = (const float*)d_in[11];
    const float* b_ih      = (const float*)d_in[12];
    const float* b_hh      = (const float*)d_in[13];
    const float* lr        = (const float*)d_in[14];

    // workspace layout (bytes, 256-aligned). part (conv split-K partials)
    // and xw_bf share region 0 — partials dead before the xw GEMM writes.
    // hseq aliases features_bf's region — features_bf dead after conv GEMM.
    char* ws = (char*)d_ws;
    float*          part     = (float*)(ws);                      // 4x4608x512 f32  37,748,736
    unsigned short* xw_bf    = (unsigned short*)(ws);             // 4608x4096 bf16 (same region)
    unsigned short* features_bf = (unsigned short*)(ws + 37748736); // 18,874,368
    unsigned short* hseq     = (unsigned short*)(ws + 37748736);  //  9,437,184 (aliases features_bf)
    unsigned short* convw_bf = (unsigned short*)(ws + 56623104);  //  2,097,152
    float*          feats    = (float*)(ws + 58720256);           //  9,529,344
    float*          hxy      = (float*)(ws + 68249600);           //  4,718,592
    unsigned short* feats_bf = (unsigned short*)(ws + 72968192);  //  5,013,504
    unsigned short* xseq_bf  = (unsigned short*)(ws + 77981696);  //  5,013,504
    unsigned short* wih_il   = (unsigned short*)(ws + 82995200);  //  4,456,448
    unsigned short* whh_il   = (unsigned short*)(ws + 87451648);  //  8,388,608
    unsigned short* wxy_bf   = (unsigned short*)(ws + 95840256);  //    278,528
    float*          comb_b   = (float*)(ws + 96118784);           //     16,384
    float*          hxy_b    = (float*)(ws + 96135168);           //      1,024
    unsigned int*   bar      = (unsigned int*)(ws + 97987584);    //      2,048 (4x128 flags)

    prep_all<<<2048, 256, 0, stream>>>(boxes, attention, features, conv_w,
                                       skew_wx, skew_wy, skew_b1, w_ih, w_hh,
                                       b_ih, b_hh, features_bf, convw_bf,
                                       wxy_bf, hxy_b, wih_il, whh_il, comb_b,
                                       bar, feats);
    // conv split-K: 128x128 tiles, K-slice 512, grid (4,36,4) = 576 blocks
    gemm128<<<dim3(4, 36, 4), 256, 0, stream>>>(features_bf, convw_bf, nullptr,
                                                (void*)part, 512, NFEAT, NFEAT, 512, 0,
                                                (long long)ROWS*512);
    conv_reduce<<<2048, 256, 0, stream>>>(part, conv_b, feats, feats_bf);
    // hxy = feats . [wx;wy]^T + [b1;0]
    gemm_mfma<<<dim3(4, 36), 256, 0, stream>>>(feats_bf, wxy_bf, hxy_b,
                                               (void*)hxy, KP, KP, KP, 256, 0);
    // fused assignment pipeline (out + 3 iters + softmax + xseq), 1 dispatch
    assign_k<<<NB, 256, 0, stream>>>(hxy, skew_w2, attention, lr,
                                     feats, xseq_bf);
    // xw = xseq . w_ih_il^T + (b_ih+b_hh) -> bf16, 128x128 tiles, 1152 blocks
    gemm128<<<dim3(32, 36, 1), 256, 0, stream>>>(xseq_bf, wih_il, comb_b,
                                                 (void*)xw_bf, KP, KP, KP, 4*NOUT, 1, 0);
    // ALL 36 LSTM steps in one persistent dispatch
    lstm_persist<<<512, 256, 0, stream>>>(whh_il, xw_bf, hseq,
                                          (float*)d_out, bar);
}

// Round 15
// 637.731 us; speedup vs baseline: 1.0437x; 1.0092x over previous
//
#include <hip/hip_runtime.h>
#include <math.h>

// Problem dims
#define NB 128
#define NN 36
#define S40 40            // padded stride, 16B-aligned rows (assign_k)
#define NFEAT 2048
#define NMID 517
#define KP 544            // padded K (multiple of 32) for MID-dim GEMMs
#define NHID 128
#define NOUT 1024
#define ROWS (NB*NN)      // 4608

typedef __bf16 bf16x8 __attribute__((ext_vector_type(8)));
typedef float  f32x4  __attribute__((ext_vector_type(4)));

__device__ __forceinline__ float sigf(float x){ return 1.f/(1.f+expf(-x)); }
__device__ __forceinline__ unsigned short f2bf(float x){
    unsigned u = __float_as_uint(x);
    return (unsigned short)((u + 0x7FFFu + ((u>>16)&1u)) >> 16);
}
__device__ __forceinline__ float bf2f(unsigned short b){
    return __uint_as_float(((unsigned)b) << 16);
}
__device__ __forceinline__ unsigned pack2(float a, float b){
    return (unsigned)f2bf(a) | ((unsigned)f2bf(b) << 16);
}
// async global->LDS, 16B/lane: LDS dest = wave-uniform base + lane*16
__device__ __forceinline__ void gload_lds16(const unsigned short* g, void* lds){
    __builtin_amdgcn_global_load_lds(
        (const __attribute__((address_space(1))) void*)g,
        (__attribute__((address_space(3))) void*)lds, 16, 0, 0);
}

// ---------------------------------------------------------------------------
// prep_all: ALL input casts/reorders/zeroing in one dispatch.
// Bulk casts vectorized (G13): float4 x2 reads + packed uint4 (8xbf16) stores.
// ---------------------------------------------------------------------------
__global__ __launch_bounds__(256) void prep_all(
    const float* __restrict__ boxes, const float* __restrict__ att,
    const float* __restrict__ features, const float* __restrict__ conv_w,
    const float* __restrict__ wx, const float* __restrict__ wy,
    const float* __restrict__ b1, const float* __restrict__ w_ih,
    const float* __restrict__ w_hh, const float* __restrict__ b_ih,
    const float* __restrict__ b_hh,
    unsigned short* __restrict__ features_bf, unsigned short* __restrict__ convw_bf,
    unsigned short* __restrict__ wxy_bf, float* __restrict__ hxy_b,
    unsigned short* __restrict__ wih_il, unsigned short* __restrict__ whh_il,
    float* __restrict__ comb_b, unsigned int* __restrict__ bar,
    float* __restrict__ feats)
{
    int gtid = blockIdx.x*256 + threadIdx.x;
    int gs = gridDim.x*256;
    if (gtid < 128*64) {
        int b = gtid >> 6, t = gtid & 63;
        float mx = -1e30f;
        for (int idx = t; idx < 4*NN; idx += 64) mx = fmaxf(mx, boxes[b*4*NN + idx]);
        for (int off = 32; off > 0; off >>= 1) mx = fmaxf(mx, __shfl_down(mx, off));
        mx = __shfl(mx, 0);
        float inv = 1.f / mx;
        for (int idx = t; idx < 4*NN; idx += 64) {
            int r = idx / NN, n = idx - r*NN;
            feats[(size_t)(b*NN+n)*NMID + r] = boxes[b*4*NN + idx] * inv;
        }
        if (t < NN) feats[(size_t)(b*NN+t)*NMID + 4] = att[b*NN + t];
    }
    // features cast: 8 elems/iter, vector load + packed 16B store
    for (int i = gtid; i < ROWS*NFEAT/8; i += gs) {
        const float* s = features + (size_t)i*8;
        float4 v0 = *(const float4*)s, v1 = *(const float4*)(s+4);
        uint4 o = { pack2(v0.x,v0.y), pack2(v0.z,v0.w),
                    pack2(v1.x,v1.y), pack2(v1.z,v1.w) };
        *(uint4*)(features_bf + (size_t)i*8) = o;
    }
    for (int i = gtid; i < 512*NFEAT/8; i += gs) {
        const float* s = conv_w + (size_t)i*8;
        float4 v0 = *(const float4*)s, v1 = *(const float4*)(s+4);
        uint4 o = { pack2(v0.x,v0.y), pack2(v0.z,v0.w),
                    pack2(v1.x,v1.y), pack2(v1.z,v1.w) };
        *(uint4*)(convw_bf + (size_t)i*8) = o;
    }
    for (int i = gtid; i < 256*KP; i += gs) {
        int r = i / KP, k = i - r*KP;
        float v = 0.f;
        if (k < NMID) v = (r < NHID) ? wx[(size_t)r*NMID+k] : wy[(size_t)(r-NHID)*NMID+k];
        wxy_bf[i] = f2bf(v);
    }
    for (int i = gtid; i < 256; i += gs) hxy_b[i] = (i < NHID) ? b1[i] : 0.f;
    // w_ih interleave: rows 4096 x KP; packed 16B stores, scalar reads
    for (int i = gtid; i < 4*NOUT*(KP/8); i += gs) {
        int row = i / (KP/8), kb = i - row*(KP/8);
        int u = row >> 2, g = row & 3;
        int base = kb*8;
        const float* s = w_ih + (size_t)(g*NOUT+u)*NMID + base;
        float f[8];
        #pragma unroll
        for (int t = 0; t < 8; ++t) f[t] = (base+t < NMID) ? s[t] : 0.f;
        uint4 o = { pack2(f[0],f[1]), pack2(f[2],f[3]),
                    pack2(f[4],f[5]), pack2(f[6],f[7]) };
        *(uint4*)(wih_il + (size_t)row*KP + base) = o;
    }
    // w_hh interleave: vector loads (1024-stride rows, 16B-aligned)
    for (int i = gtid; i < 4*NOUT*NOUT/8; i += gs) {
        int row = i >> 7, kb = i & 127;
        int u = row >> 2, g = row & 3;
        const float* s = w_hh + ((size_t)(g*NOUT+u) << 10) + kb*8;
        float4 v0 = *(const float4*)s, v1 = *(const float4*)(s+4);
        uint4 o = { pack2(v0.x,v0.y), pack2(v0.z,v0.w),
                    pack2(v1.x,v1.y), pack2(v1.z,v1.w) };
        *(uint4*)(whh_il + ((size_t)row << 10) + kb*8) = o;
    }
    for (int i = gtid; i < 4*NOUT; i += gs) {
        int u = i >> 2, g = i & 3;
        comb_b[i] = b_ih[g*NOUT+u] + b_hh[g*NOUT+u];
    }
    // persistent-LSTM producer flags: 4 bt-groups x 128 blocks, monotonic epoch
    for (int i = gtid; i < 512; i += gs) bar[i] = 0u;
}

// ---------------------------------------------------------------------------
// gemm128: block tile 128x128, 4 waves = 2x2, wave tile 64x64.
// global_load_lds width=16 staging with inverse-swizzled per-lane source.
// ---------------------------------------------------------------------------
__global__ __launch_bounds__(256) void gemm128(
    const unsigned short* __restrict__ A, const unsigned short* __restrict__ B,
    const float* __restrict__ bias, void* __restrict__ Cp,
    int Ksl, int lda, int ldb, int ldc, int obf, long long pstride)
{
    __shared__ __align__(16) char As[16384];
    __shared__ __align__(16) char Bs[16384];
    int m0 = blockIdx.y * 128, n0 = blockIdx.x * 128;
    int kbeg = blockIdx.z * Ksl;
    int tid = threadIdx.x;
    int lane = tid & 63, wave = tid >> 6;
    int wm = wave >> 1, wn = wave & 1;
    int sw = ((lane>>4)<<8) + (((lane&15) ^ ((lane>>4)<<2))<<4);
    f32x4 acc[4][4];
    #pragma unroll
    for (int i = 0; i < 4; ++i)
        #pragma unroll
        for (int j = 0; j < 4; ++j) acc[i][j] = (f32x4){0.f,0.f,0.f,0.f};

    int gq = lane >> 4, sl = lane & 15;
    int rloc = sl ^ (gq << 2);
    int g0r = wave*2*16 + rloc, g1r = g0r + 16;
    const unsigned short* a0 = A + (size_t)(m0 + g0r)*lda + kbeg + gq*8;
    const unsigned short* a1 = A + (size_t)(m0 + g1r)*lda + kbeg + gq*8;
    const unsigned short* b0 = B + (size_t)(n0 + g0r)*ldb + kbeg + gq*8;
    const unsigned short* b1 = B + (size_t)(n0 + g1r)*ldb + kbeg + gq*8;
    char* asd0 = As + ((wave*2)<<10); char* asd1 = asd0 + 1024;
    char* bsd0 = Bs + ((wave*2)<<10); char* bsd1 = bsd0 + 1024;

    for (int k0 = 0; k0 < Ksl; k0 += 32) {
        gload_lds16(a0 + k0, asd0);
        gload_lds16(a1 + k0, asd1);
        gload_lds16(b0 + k0, bsd0);
        gload_lds16(b1 + k0, bsd1);
        __syncthreads();
        bf16x8 af[4], bfr[4];
        #pragma unroll
        for (int i = 0; i < 4; ++i) af[i]  = *(bf16x8*)(As + ((wm*4+i)<<10) + sw);
        #pragma unroll
        for (int j = 0; j < 4; ++j) bfr[j] = *(bf16x8*)(Bs + ((wn*4+j)<<10) + sw);
        #pragma unroll
        for (int i = 0; i < 4; ++i)
            #pragma unroll
            for (int j = 0; j < 4; ++j)
                acc[i][j] = __builtin_amdgcn_mfma_f32_16x16x32_bf16(af[i], bfr[j], acc[i][j], 0, 0, 0);
        __syncthreads();
    }
    int colf = lane & 15, rowq = lane >> 4;
    #pragma unroll
    for (int j = 0; j < 4; ++j) {
        int col = n0 + (wn*4+j)*16 + colf;
        float bv = bias ? bias[col] : 0.f;
        #pragma unroll
        for (int i = 0; i < 4; ++i) {
            #pragma unroll
            for (int reg = 0; reg < 4; ++reg) {
                int row = m0 + (wm*4+i)*16 + rowq*4 + reg;
                float v = acc[i][j][reg] + bv;
                if (obf) ((unsigned short*)Cp)[(size_t)row*ldc + col] = f2bf(v);
                else ((float*)Cp + (size_t)blockIdx.z*pstride)[(size_t)row*ldc + col] = v;
            }
        }
    }
}

// ---------------------------------------------------------------------------
// conv_reduce: feats[:,5:] = sum_z part[z] + conv_b; emits full padded bf16
// feats (cols 0..4 from feats, 5..516 computed, 517..543 zero).
// ---------------------------------------------------------------------------
__global__ __launch_bounds__(256) void conv_reduce(
    const float* __restrict__ part, const float* __restrict__ bias,
    float* __restrict__ feats, unsigned short* __restrict__ feats_bf)
{
    int gtid = blockIdx.x*256 + threadIdx.x;
    int gs = gridDim.x*256;
    const size_t PS = (size_t)ROWS * 512;
    for (int i = gtid; i < ROWS*512; i += gs) {
        int r = i >> 9, cc = i & 511;
        float s = part[i] + part[PS+i] + part[2*PS+i] + part[3*PS+i] + bias[cc];
        feats[(size_t)r*NMID + 5 + cc] = s;
        feats_bf[(size_t)r*KP + 5 + cc] = f2bf(s);
    }
    for (int i = gtid; i < ROWS*5; i += gs) {
        int r = i / 5, cc = i - r*5;
        feats_bf[(size_t)r*KP + cc] = f2bf(feats[(size_t)r*NMID + cc]);
    }
    for (int i = gtid; i < ROWS*27; i += gs) {
        int r = i / 27, cc = i - r*27;
        feats_bf[(size_t)r*KP + 517 + cc] = 0;
    }
}

// ---------------------------------------------------------------------------
// bf16 MFMA GEMM (hxy only): tile 128x64, wave tile 64x32.
// global_load_lds staging (linear LDS).
// ---------------------------------------------------------------------------
__global__ __launch_bounds__(256) void gemm_mfma(
    const unsigned short* __restrict__ A, const unsigned short* __restrict__ B,
    const float* __restrict__ bias, void* __restrict__ Cp,
    int K, int lda, int ldb, int ldc, int obf)
{
    __shared__ __align__(16) char As[8192];
    __shared__ __align__(16) char Bs[4096];
    int m0 = blockIdx.y * 128, n0 = blockIdx.x * 64;
    int tid = threadIdx.x;
    int lane = tid & 63, wave = tid >> 6;
    int wm = wave >> 1, wn = wave & 1;
    f32x4 acc[4][2];
    #pragma unroll
    for (int i = 0; i < 4; ++i)
        #pragma unroll
        for (int j = 0; j < 2; ++j) acc[i][j] = (f32x4){0.f,0.f,0.f,0.f};

    int gq = lane >> 4, sl = lane & 15;
    int g0r = wave*2*16 + sl, g1r = g0r + 16;
    const unsigned short* a0 = A + (size_t)(m0 + g0r)*lda + gq*8;
    const unsigned short* a1 = A + (size_t)(m0 + g1r)*lda + gq*8;
    const unsigned short* bb0 = B + (size_t)(n0 + wave*16 + sl)*ldb + gq*8;
    char* asd0 = As + ((wave*2)<<10); char* asd1 = asd0 + 1024;
    char* bsd0 = Bs + (wave<<10);

    for (int k0 = 0; k0 < K; k0 += 32) {
        gload_lds16(a0 + k0, asd0);
        gload_lds16(a1 + k0, asd1);
        gload_lds16(bb0 + k0, bsd0);
        __syncthreads();
        bf16x8 af[4], bfr[2];
        #pragma unroll
        for (int i = 0; i < 4; ++i) af[i]  = *(bf16x8*)(As + ((wm*4+i)<<10) + (lane<<4));
        #pragma unroll
        for (int j = 0; j < 2; ++j) bfr[j] = *(bf16x8*)(Bs + ((wn*2+j)<<10) + (lane<<4));
        #pragma unroll
        for (int i = 0; i < 4; ++i)
            #pragma unroll
            for (int j = 0; j < 2; ++j)
                acc[i][j] = __builtin_amdgcn_mfma_f32_16x16x32_bf16(af[i], bfr[j], acc[i][j], 0, 0, 0);
        __syncthreads();
    }
    int colf = lane & 15, rowq = lane >> 4;
    #pragma unroll
    for (int j = 0; j < 2; ++j) {
        int col = n0 + (wn*2+j)*16 + colf;
        float bv = bias ? bias[col] : 0.f;
        #pragma unroll
        for (int i = 0; i < 4; ++i) {
            #pragma unroll
            for (int reg = 0; reg < 4; ++reg) {
                int row = m0 + (wm*4+i)*16 + rowq*4 + reg;
                float v = acc[i][j][reg] + bv;
                if (obf) ((unsigned short*)Cp)[(size_t)row*ldc + col] = f2bf(v);
                else     ((float*)Cp)[(size_t)row*ldc + col] = v;
            }
        }
    }
}

// ---------------------------------------------------------------------------
// assign_k: FUSED out_k + iter_k + xseq_k. Grid 128, one block per batch b.
// ---------------------------------------------------------------------------
__global__ __launch_bounds__(256) void assign_k(
    const float* __restrict__ hxy, const float* __restrict__ w2,
    const float* __restrict__ att, const float* __restrict__ lr,
    const float* __restrict__ feats, unsigned short* __restrict__ xseq)
{
    __shared__ float s_hx[NN*129], s_hy[NN*129], s_w2[NHID], s_sg[NN];
    __shared__ __align__(16) float s_C[NN*S40], s_logits[NN*S40], s_P[NN*S40];
    int b = blockIdx.x, tid = threadIdx.x;
    for (int i = tid; i < NN*NHID; i += 256) {
        int n = i >> 7, h = i & 127;
        s_hx[n*129+h] = hxy[(size_t)(b*NN+n)*256 + h];
        s_hy[n*129+h] = hxy[(size_t)(b*NN+n)*256 + 128 + h];
    }
    if (tid < NHID) s_w2[tid] = w2[tid];
    if (tid < NN) s_sg[tid] = sigf(att[b*NN + tid]);
    float lr_abs = fabsf(lr[0]);
    __syncthreads();
    for (int idx = tid; idx < NN*NN; idx += 256) {
        int i = idx / NN, j = idx - i*NN;
        const float* px = &s_hx[i*129];
        const float* py = &s_hy[j*129];
        float s = 0.f;
        #pragma unroll 8
        for (int h = 0; h < NHID; ++h) s += s_w2[h] * fmaxf(px[h] + py[h], 0.f);
        s_logits[i*S40+j] = s;
    }
    __syncthreads();
    for (int idx = tid; idx < NN*NN; idx += 256) {
        int i = idx / NN, j = idx - i*NN;
        s_C[i*S40+j] = s_logits[i*S40+j] - s_logits[j*S40+i];
    }
    __syncthreads();
    for (int idx = tid; idx < NN*NN; idx += 256) {
        int i = idx / NN, j = idx - i*NN;
        s_logits[i*S40+j] = 0.f;
    }
    __syncthreads();
    for (int it = 0; it < 3; ++it) {
        if (tid < NN) {
            int i = tid;
            float mx = -1e30f;
            for (int l = 0; l < NN; ++l) mx = fmaxf(mx, s_logits[i*S40+l]);
            float sum = 0.f;
            for (int l = 0; l < NN; ++l) { float e = expf(s_logits[i*S40+l]-mx); s_P[i*S40+l] = e; sum += e; }
            float inv = 1.f/sum;
            for (int l = 0; l < NN; ++l) s_P[i*S40+l] *= inv;
        }
        __syncthreads();
        if (tid < NN) {
            int l = tid;
            float S = 0.f;
            for (int i = 0; i < NN; ++i) S += s_P[i*S40+l];
            float cum = 0.f;
            for (int i = 0; i < NN; ++i) {
                float p = s_P[i*S40+l];
                cum += p;
                s_P[i*S40+l] = S - 2.f*cum + p;
            }
        }
        __syncthreads();
        for (int idx = tid; idx < NN*NN; idx += 256) {
            int i = idx / NN, j = idx - i*NN;
            const f32x4* Pp = (const f32x4*)&s_P[i*S40];
            const f32x4* Cc = (const f32x4*)&s_C[j*S40];
            float g = 0.f;
            #pragma unroll
            for (int q = 0; q < 9; ++q) {
                f32x4 a = Pp[q], bb = Cc[q];
                g += a[0]*bb[0] + a[1]*bb[1] + a[2]*bb[2] + a[3]*bb[3];
            }
            s_logits[i*S40+j] -= lr_abs * g;
        }
        __syncthreads();
    }
    if (tid < NN) {
        int i = tid;
        float mx = -1e30f;
        for (int l = 0; l < NN; ++l) mx = fmaxf(mx, s_logits[i*S40+l]);
        float sum = 0.f;
        for (int l = 0; l < NN; ++l) { float e = expf(s_logits[i*S40+l]-mx); s_P[i*S40+l] = e; sum += e; }
        float inv = 1.f/sum;
        for (int l = 0; l < NN; ++l) s_P[i*S40+l] *= inv * s_sg[l];
    }
    __syncthreads();
    const float* fb = feats + (size_t)b*NN*NMID;
    #pragma unroll
    for (int rep = 0; rep < 3; ++rep) {
        int c = rep*256 + tid;
        if (c < KP) {
            float colv[NN];
            #pragma unroll
            for (int l = 0; l < NN; ++l) colv[l] = (c < NMID) ? fb[l*NMID + c] : 0.f;
            #pragma unroll 4
            for (int i = 0; i < NN; ++i) {
                float s = 0.f;
                #pragma unroll
                for (int l = 0; l < NN; ++l) s += s_P[i*S40+l] * colv[l];
                xseq[((size_t)i*NB + b)*KP + c] = f2bf(s);
            }
        }
    }
}

// ---------------------------------------------------------------------------
// lstm_persist: pipelined chunk waits + double-buffered h loads.
// CONTIGUOUS bt-group decode (bt = blockIdx>>7): each dependency group is a
// contiguous blockIdx range; in-order dispatch + group retirement guarantee
// progress for any co-resident capacity >= 128. Proven structure (r7-r11,
// 367-378us, total 643.6us).
// ---------------------------------------------------------------------------
__global__ __launch_bounds__(256, 2) void lstm_persist(
    const unsigned short* __restrict__ whh, const unsigned short* __restrict__ xw,
    unsigned short* __restrict__ hseq, float* __restrict__ dout,
    unsigned int* __restrict__ bar)
{
    __shared__ __align__(16) char Bls[65536];    // [kc 0..127][n' 0..31][16B]
    __shared__ __align__(16) float gates[32][36];
    int tid = threadIdx.x, lane = tid & 63, wave = tid >> 6;
    int bt = blockIdx.x >> 7, ct = blockIdx.x & 127;
    int m0 = bt * 32, n0 = ct * 32;
    // stage whh slice ONCE: 16 passes; each wave reads 1KB contiguous/row
    #pragma unroll
    for (int r = 0; r < 16; ++r) {
        int idx = r*256 + tid;
        int n = idx >> 7, kc = idx & 127;
        uint4 v = *(const uint4*)(whh + (size_t)(n0+n)*NOUT + kc*8);
        *(uint4*)(Bls + kc*512 + (((n&16) | ((n^kc)&15))<<4)) = v;
    }
    int wm = wave >> 1, wn = wave & 1;
    int q = lane >> 4, ml = lane & 15;
    int nl = wn*16 + ml;
    int ul = tid & 7, bl = tid >> 3;
    int b = m0 + bl, u = ct*8 + ul;
    unsigned int* flags = bar + bt*128;          // this group's 128 flags
    int fidx = lane & 31;                        // lane's flag slot in a chunk
    float cc = 0.f;
    __syncthreads();
    for (int t = 0; t < NN; ++t) {
        // xw contribution (includes b_ih+b_hh from the xw GEMM epilogue)
        uint2 xw2 = *(const uint2*)(xw + ((size_t)t*NB + b)*4*NOUT + n0 + ul*4);
        float g0 = bf2f((unsigned short)(xw2.x & 0xffffu));
        float g1 = bf2f((unsigned short)(xw2.x >> 16));
        float g2 = bf2f((unsigned short)(xw2.y & 0xffffu));
        float g3 = bf2f((unsigned short)(xw2.y >> 16));
        if (t > 0) {
            const unsigned short* hrow = hseq + (size_t)(t-1)*NB*NOUT
                                       + (size_t)(m0 + wm*16 + ml)*NOUT + q*8;
            f32x4 acc = (f32x4){0.f,0.f,0.f,0.f};
            unsigned tgt = (unsigned)t;
            bf16x8 abuf[2][8];
            // chunk 0: wait + issue loads
            for (;;) {
                unsigned f = __hip_atomic_load(flags + fidx,
                                  __ATOMIC_RELAXED, __HIP_MEMORY_SCOPE_AGENT);
                if (__all(f >= tgt)) break;
                __builtin_amdgcn_s_sleep(1);
            }
            asm volatile("" ::: "memory");   // no load hoisting above spin
            #pragma unroll
            for (int i = 0; i < 8; ++i)
                abuf[0][i] = *(const bf16x8*)(hrow + i*32);
            #pragma unroll
            for (int c = 0; c < 4; ++c) {
                if (c < 3) {
                    // wait for chunk c+1's producers; chunk c's loads fly
                    for (;;) {
                        unsigned f = __hip_atomic_load(flags + 32*(c+1) + fidx,
                                          __ATOMIC_RELAXED, __HIP_MEMORY_SCOPE_AGENT);
                        if (__all(f >= tgt)) break;
                        __builtin_amdgcn_s_sleep(1);
                    }
                    asm volatile("" ::: "memory");
                    #pragma unroll
                    for (int i = 0; i < 8; ++i)
                        abuf[(c+1)&1][i] = *(const bf16x8*)(hrow + ((c+1)*8 + i)*32);
                }
                // MFMA chunk c (loads(c+1) in flight behind these)
                #pragma unroll
                for (int it2 = 0; it2 < 8; ++it2) {
                    int kc = (c*8 + it2)*4 + q;
                    bf16x8 bb = *(const bf16x8*)(Bls + kc*512 + (((nl&16) | ((nl^kc)&15))<<4));
                    acc = __builtin_amdgcn_mfma_f32_16x16x32_bf16(abuf[c&1][it2], bb, acc, 0, 0, 0);
                }
            }
            #pragma unroll
            for (int reg = 0; reg < 4; ++reg)
                gates[wm*16 + q*4 + reg][wn*16 + ml] = acc[reg];
            __syncthreads();
            float4 gl = *(const float4*)&gates[bl][ul*4];
            g0 += gl.x; g1 += gl.y; g2 += gl.z; g3 += gl.w;
        }
        float ig = sigf(g0), fg = sigf(g1), gg = tanhf(g2), og = sigf(g3);
        cc = fg*cc + ig*gg;
        if (t == NN-1) {
            dout[(size_t)b*NOUT + u] = cc;
        } else {
            // lane-pair pack -> native 32-bit sc1 write-through store
            unsigned short hb = f2bf(og*tanhf(cc));
            unsigned partner = (unsigned)__shfl_down((int)(unsigned)hb, 1);
            if ((ul & 1) == 0) {
                unsigned word = (unsigned)hb | (partner << 16);
                unsigned* dst = (unsigned*)(hseq + (size_t)t*NB*NOUT
                                            + (size_t)b*NOUT + u);
                __hip_atomic_store(dst, word, __ATOMIC_RELAXED,
                                   __HIP_MEMORY_SCOPE_AGENT);
            }
            asm volatile("s_waitcnt vmcnt(0)" ::: "memory"); // h at coherent point
            __syncthreads();            // all threads drained + gates reads done
            if (tid == 0)
                __hip_atomic_store(flags + ct, (unsigned)(t + 1),
                                   __ATOMIC_RELAXED, __HIP_MEMORY_SCOPE_AGENT);
            // NO wait here — next step's chunk waits pipeline the latency
        }
    }
}

// ---------------------------------------------------------------------------
extern "C" void kernel_launch(void* const* d_in, const int* in_sizes, int n_in,
                              void* d_out, int out_size, void* d_ws, size_t ws_size,
                              hipStream_t stream) {
    (void)in_sizes; (void)n_in; (void)out_size; (void)ws_size;
    const float* boxes     = (const float*)d_in[0];
    const float* attention = (const float*)d_in[1];
    const float* features  = (const float*)d_in[2];
    const float* conv_w    = (const float*)d_in[3];
    const float* conv_b    = (const float*)d_in[4];
    const float* skew_wx   = (const float*)d_in[5];
    const float* skew_wy   = (const float*)d_in[6];
    const float* skew_b1   = (const float*)d_in[7];
    const float* skew_w2   = (const float*)d_in[8];
    // d_in[9] = skew_b2: cancels in C = out - out^T
    const float* w_ih      = (const float*)d_in[10];
    const float* w_hh      = (const float*)d_in[11];
    const float* b_ih      = (const float*)d_in[12];
    const float* b_hh      = (const float*)d_in[13];
    const float* lr        = (const float*)d_in[14];

    // workspace layout (bytes, 256-aligned). part (conv split-K partials)
    // and xw_bf share region 0 — partials dead before the xw GEMM writes.
    // hseq aliases features_bf's region — features_bf dead after conv GEMM.
    char* ws = (char*)d_ws;
    float*          part     = (float*)(ws);                      // 4x4608x512 f32  37,748,736
    unsigned short* xw_bf    = (unsigned short*)(ws);             // 4608x4096 bf16 (same region)
    unsigned short* features_bf = (unsigned short*)(ws + 37748736); // 18,874,368
    unsigned short* hseq     = (unsigned short*)(ws + 37748736);  //  9,437,184 (aliases features_bf)
    unsigned short* convw_bf = (unsigned short*)(ws + 56623104);  //  2,097,152
    float*          feats    = (float*)(ws + 58720256);           //  9,529,344
    float*          hxy      = (float*)(ws + 68249600);           //  4,718,592
    unsigned short* feats_bf = (unsigned short*)(ws + 72968192);  //  5,013,504
    unsigned short* xseq_bf  = (unsigned short*)(ws + 77981696);  //  5,013,504
    unsigned short* wih_il   = (unsigned short*)(ws + 82995200);  //  4,456,448
    unsigned short* whh_il   = (unsigned short*)(ws + 87451648);  //  8,388,608
    unsigned short* wxy_bf   = (unsigned short*)(ws + 95840256);  //    278,528
    float*          comb_b   = (float*)(ws + 96118784);           //     16,384
    float*          hxy_b    = (float*)(ws + 96135168);           //      1,024
    unsigned int*   bar      = (unsigned int*)(ws + 97987584);    //      2,048 (4x128 flags)

    prep_all<<<2048, 256, 0, stream>>>(boxes, attention, features, conv_w,
                                       skew_wx, skew_wy, skew_b1, w_ih, w_hh,
                                       b_ih, b_hh, features_bf, convw_bf,
                                       wxy_bf, hxy_b, wih_il, whh_il, comb_b,
                                       bar, feats);
    // conv split-K: 128x128 tiles, K-slice 512, grid (4,36,4) = 576 blocks
    gemm128<<<dim3(4, 36, 4), 256, 0, stream>>>(features_bf, convw_bf, nullptr,
                                                (void*)part, 512, NFEAT, NFEAT, 512, 0,
                                                (long long)ROWS*512);
    conv_reduce<<<2048, 256, 0, stream>>>(part, conv_b, feats, feats_bf);
    // hxy = feats . [wx;wy]^T + [b1;0]
    gemm_mfma<<<dim3(4, 36), 256, 0, stream>>>(feats_bf, wxy_bf, hxy_b,
                                               (void*)hxy, KP, KP, KP, 256, 0);
    // fused assignment pipeline (out + 3 iters + softmax + xseq), 1 dispatch
    assign_k<<<NB, 256, 0, stream>>>(hxy, skew_w2, attention, lr,
                                     feats, xseq_bf);
    // xw = xseq . w_ih_il^T + (b_ih+b_hh) -> bf16, 128x128 tiles, 1152 blocks
    gemm128<<<dim3(32, 36, 1), 256, 0, stream>>>(xseq_bf, wih_il, comb_b,
                                                 (void*)xw_bf, KP, KP, KP, 4*NOUT, 1, 0);
    // ALL 36 LSTM steps in one persistent dispatch (contiguous bt-groups)
    lstm_persist<<<512, 256, 0, stream>>>(whh_il, xw_bf, hseq,
                                          (float*)d_out, bar);
}